// Round 1
// baseline (2295.178 us; speedup 1.0000x reference)
//
#include <hip/hip_runtime.h>
#include <hip/hip_bf16.h>
#include <math.h>

#define NNODES 20000
#define NEDGES 320000
#define HEADS  4
#define DDIM   256
#define MCOLS  1024   // H*D

// ---------------- CSR build (by dst) ----------------
__global__ void k_zero(int* deg, int n) {
  int i = blockIdx.x*blockDim.x + threadIdx.x;
  if (i < n) deg[i] = 0;
}
__global__ void k_hist(const int* __restrict__ dst, int* deg, int e) {
  int i = blockIdx.x*blockDim.x + threadIdx.x;
  if (i < e) atomicAdd(&deg[dst[i]], 1);
}
__global__ void k_scan(const int* __restrict__ deg, int* row_ptr, int* cursor) {
  __shared__ int sm[1024];
  int t = threadIdx.x;
  const int CH = 20;               // 1024*20 >= 20000
  int base = t*CH;
  int s = 0;
  #pragma unroll
  for (int i = 0; i < CH; ++i) { int idx = base+i; if (idx < NNODES) s += deg[idx]; }
  int val = s;
  sm[t] = s; __syncthreads();
  for (int off = 1; off < 1024; off <<= 1) {
    int add = (t >= off) ? sm[t-off] : 0;
    __syncthreads();
    val += add; sm[t] = val;
    __syncthreads();
  }
  int run = val - s;               // exclusive prefix for this chunk
  for (int i = 0; i < CH; ++i) {
    int idx = base+i;
    if (idx < NNODES) { row_ptr[idx] = run; cursor[idx] = run; run += deg[idx]; }
  }
  if (t == 0) row_ptr[NNODES] = NEDGES;
}
__global__ void k_fill(const int* __restrict__ src, const int* __restrict__ dst,
                       int* cursor, int* srcs_sorted, int e) {
  int i = blockIdx.x*blockDim.x + threadIdx.x;
  if (i < e) { int pos = atomicAdd(&cursor[dst[i]], 1); srcs_sorted[pos] = src[i]; }
}

// ---------------- Wred[k,h] = sum_d Wdst[k, h*D+d] * ar[h,d] ----------------
__global__ void k_wred(const float* __restrict__ Wdst, const float* __restrict__ ar,
                       float* __restrict__ Wred, int K) {
  int wave = threadIdx.x >> 6, lane = threadIdx.x & 63;
  int p = blockIdx.x*4 + wave;          // pair index = k*HEADS + h
  if (p >= K*HEADS) return;
  int k = p >> 2, h = p & 3;
  const float4 wv = *(const float4*)&Wdst[(size_t)k*MCOLS + h*DDIM + lane*4];
  const float4 av = *(const float4*)&ar[h*DDIM + lane*4];
  float s = wv.x*av.x + wv.y*av.y + wv.z*av.z + wv.w*av.w;
  for (int off = 32; off; off >>= 1) s += __shfl_xor(s, off);
  if (lane == 0) Wred[k*HEADS + h] = s;
}

// ---------------- fp32 GEMM: C[nrows,1024] = A[nrows,K] @ W[K,1024] ----------------
__global__ __launch_bounds__(256) void k_gemm(const float* __restrict__ A,
                                              const float* __restrict__ W,
                                              float* __restrict__ C, int nrows, int K) {
  __shared__ float As[16][68];   // [k][m], pad 68 keeps float4 alignment + spreads banks
  __shared__ float Ws[16][64];   // [k][n]
  int tid  = threadIdx.x;
  int row0 = blockIdx.y*64, col0 = blockIdx.x*64;
  int ty = tid >> 4, tx = tid & 15;
  int lrow = tid >> 2, lk4 = (tid & 3)*4;   // A-tile load: 64 rows x 4 float4
  int wk = tid >> 4, wn4 = (tid & 15)*4;    // W-tile load: 16 rows x 16 float4
  float acc[4][4];
  #pragma unroll
  for (int i = 0; i < 4; ++i)
    #pragma unroll
    for (int j = 0; j < 4; ++j) acc[i][j] = 0.f;
  int arow = row0 + lrow; if (arow >= nrows) arow = nrows - 1;
  const float* Aptr = A + (size_t)arow*K + lk4;
  const float* Wptr = W + (size_t)wk*MCOLS + col0 + wn4;
  for (int k0 = 0; k0 < K; k0 += 16) {
    float4 av = *(const float4*)(Aptr + k0);
    float4 wv = *(const float4*)(Wptr + (size_t)k0*MCOLS);
    As[lk4+0][lrow] = av.x; As[lk4+1][lrow] = av.y;
    As[lk4+2][lrow] = av.z; As[lk4+3][lrow] = av.w;
    *(float4*)&Ws[wk][wn4] = wv;
    __syncthreads();
    #pragma unroll
    for (int k = 0; k < 16; ++k) {
      float a[4], b[4];
      *(float4*)a = *(const float4*)&As[k][ty*4];
      *(float4*)b = *(const float4*)&Ws[k][tx*4];
      #pragma unroll
      for (int i = 0; i < 4; ++i)
        #pragma unroll
        for (int j = 0; j < 4; ++j) acc[i][j] = fmaf(a[i], b[j], acc[i][j]);
    }
    __syncthreads();
  }
  #pragma unroll
  for (int i = 0; i < 4; ++i) {
    int r = row0 + ty*4 + i;
    if (r < nrows) {
      float4 o = make_float4(acc[i][0], acc[i][1], acc[i][2], acc[i][3]);
      *(float4*)&C[(size_t)r*MCOLS + col0 + tx*4] = o;
    }
  }
}

// ---------------- el[n,h] = sum_d fs[n,h,d]*al[h,d] ----------------
__global__ void k_el(const float* __restrict__ fs, const float* __restrict__ al,
                     float* __restrict__ el) {
  int n = blockIdx.x;
  int h = threadIdx.x >> 6, lane = threadIdx.x & 63;
  const float4 f = *(const float4*)&fs[(size_t)n*MCOLS + h*DDIM + lane*4];
  const float4 a = *(const float4*)&al[h*DDIM + lane*4];
  float s = f.x*a.x + f.y*a.y + f.z*a.z + f.w*a.w;
  for (int off = 32; off; off >>= 1) s += __shfl_xor(s, off);
  if (lane == 0) el[n*HEADS + h] = s;
}

// ---------------- er[n,h] = sum_k hin[n,k]*Wred[k,h] ----------------
__global__ void k_er(const float* __restrict__ hin, const float* __restrict__ Wred,
                     float* __restrict__ er, int K) {
  int n = blockIdx.x;
  int h = threadIdx.x >> 6, lane = threadIdx.x & 63;
  float s = 0.f;
  for (int k = lane; k < K; k += 64) s += hin[(size_t)n*K + k] * Wred[k*HEADS + h];
  for (int off = 32; off; off >>= 1) s += __shfl_xor(s, off);
  if (lane == 0) er[n*HEADS + h] = s;
}

// ---------------- per-dst softmax + weighted aggregation ----------------
// mode 0: out[n,1024] = relu(agg + b)         (layers 0,1)
// mode 1: out[n,256]  = mean_h(agg + b)       (layer 2, no act)
__global__ void k_agg(const float* __restrict__ fs, const float* __restrict__ el,
                      const float* __restrict__ er, const int* __restrict__ row_ptr,
                      const int* __restrict__ srcs, const float* __restrict__ bias,
                      float* __restrict__ out, int mode) {
  __shared__ float sm[HEADS*DDIM];
  int n = blockIdx.x;
  int h = threadIdx.x >> 6, lane = threadIdx.x & 63;
  int beg = row_ptr[n], end = row_ptr[n+1];
  float er_nh = er[n*HEADS + h];
  // pass 1: segment max (lanes stride edges, then wave max-reduce)
  float m = -INFINITY;
  for (int i = beg + lane; i < end; i += 64) {
    int s = srcs[i];
    float e = el[s*HEADS + h] + er_nh;
    e = e >= 0.f ? e : 0.2f*e;
    m = fmaxf(m, e);
  }
  for (int off = 32; off; off >>= 1) m = fmaxf(m, __shfl_xor(m, off));
  // pass 2: den + weighted accumulation (lanes serve D, float4 each)
  float den = 0.f;
  float4 acc = make_float4(0.f, 0.f, 0.f, 0.f);
  const float* fsh = fs + h*DDIM + lane*4;
  for (int i = beg; i < end; ++i) {
    int s = srcs[i];
    float e = el[s*HEADS + h] + er_nh;
    e = e >= 0.f ? e : 0.2f*e;
    float w = expf(e - m);
    den += w;
    const float4 v = *(const float4*)&fsh[(size_t)s*MCOLS];
    acc.x = fmaf(w, v.x, acc.x);
    acc.y = fmaf(w, v.y, acc.y);
    acc.z = fmaf(w, v.z, acc.z);
    acc.w = fmaf(w, v.w, acc.w);
  }
  float inv = den > 0.f ? 1.f/den : 0.f;   // zero in-degree -> out = bias
  const float4 bv = *(const float4*)&bias[h*DDIM + lane*4];
  acc.x = acc.x*inv + bv.x;
  acc.y = acc.y*inv + bv.y;
  acc.z = acc.z*inv + bv.z;
  acc.w = acc.w*inv + bv.w;
  if (mode == 0) {
    acc.x = fmaxf(acc.x, 0.f); acc.y = fmaxf(acc.y, 0.f);
    acc.z = fmaxf(acc.z, 0.f); acc.w = fmaxf(acc.w, 0.f);
    *(float4*)&out[(size_t)n*MCOLS + h*DDIM + lane*4] = acc;
  } else {
    *(float4*)&sm[h*DDIM + lane*4] = acc;
    __syncthreads();
    int t = threadIdx.x;   // 256 threads <-> 256 dims
    out[(size_t)n*DDIM + t] =
        0.25f*(sm[t] + sm[DDIM + t] + sm[2*DDIM + t] + sm[3*DDIM + t]);
  }
}

extern "C" void kernel_launch(void* const* d_in, const int* in_sizes, int n_in,
                              void* d_out, int out_size, void* d_ws, size_t ws_size,
                              hipStream_t stream) {
  const float* x   = (const float*)d_in[0];
  const int*   src = (const int*)d_in[1];
  const int*   dst = (const int*)d_in[2];
  const float* Wsrc[3] = {(const float*)d_in[3], (const float*)d_in[8],  (const float*)d_in[13]};
  const float* Wdst[3] = {(const float*)d_in[4], (const float*)d_in[9],  (const float*)d_in[14]};
  const float* al[3]   = {(const float*)d_in[5], (const float*)d_in[10], (const float*)d_in[15]};
  const float* ar[3]   = {(const float*)d_in[6], (const float*)d_in[11], (const float*)d_in[16]};
  const float* bb[3]   = {(const float*)d_in[7], (const float*)d_in[12], (const float*)d_in[17]};

  char* ws = (char*)d_ws;
  size_t off = 0;
  auto alloc = [&](size_t bytes) { void* p = ws + off; off += (bytes + 255) & ~255ull; return p; };
  float* bufA = (float*)alloc((size_t)NNODES*MCOLS*4);   // h (layer activations)
  float* bufB = (float*)alloc((size_t)NNODES*MCOLS*4);   // fs (src projection)
  float* elb  = (float*)alloc((size_t)NNODES*HEADS*4);
  float* erb  = (float*)alloc((size_t)NNODES*HEADS*4);
  float* Wred = (float*)alloc(1024*HEADS*4);
  int* deg     = (int*)alloc((size_t)NNODES*4);
  int* row_ptr = (int*)alloc((size_t)(NNODES+1)*4);
  int* cursor  = (int*)alloc((size_t)NNODES*4);
  int* srcs    = (int*)alloc((size_t)NEDGES*4);
  (void)ws_size; (void)in_sizes; (void)n_in; (void)out_size;

  // CSR build (graph identical across layers)
  k_zero<<<(NNODES+255)/256, 256, 0, stream>>>(deg, NNODES);
  k_hist<<<(NEDGES+255)/256, 256, 0, stream>>>(dst, deg, NEDGES);
  k_scan<<<1, 1024, 0, stream>>>(deg, row_ptr, cursor);
  k_fill<<<(NEDGES+255)/256, 256, 0, stream>>>(src, dst, cursor, srcs, NEDGES);

  const int Fin[3] = {512, 1024, 1024};
  const float* hin = x;
  for (int l = 0; l < 3; ++l) {
    int K = Fin[l];
    k_wred<<<K, 256, 0, stream>>>(Wdst[l], ar[l], Wred, K);   // K*HEADS/4 == K blocks
    dim3 g(MCOLS/64, (NNODES+63)/64);
    k_gemm<<<g, 256, 0, stream>>>(hin, Wsrc[l], bufB, NNODES, K);
    k_el<<<NNODES, 256, 0, stream>>>(bufB, al[l], elb);
    k_er<<<NNODES, 256, 0, stream>>>(hin, Wred, erb, K);
    float* outp = (l == 2) ? (float*)d_out : bufA;
    k_agg<<<NNODES, 256, 0, stream>>>(bufB, elb, erb, row_ptr, srcs, bb[l], outp, l == 2 ? 1 : 0);
    hin = bufA;
  }
}

// Round 2
// 1407.298 us; speedup vs baseline: 1.6309x; 1.6309x over previous
//
#include <hip/hip_runtime.h>
#include <hip/hip_bf16.h>
#include <math.h>

#define NNODES 20000
#define NPAD   20096   // 157 * 128
#define NEDGES 320000
#define HEADS  4
#define DDIM   256
#define MCOLS  1024   // H*D

typedef __attribute__((ext_vector_type(8))) short short8;
typedef __attribute__((ext_vector_type(4))) float f32x4;

// bf16 helpers (bit-level, RNE)
__device__ __forceinline__ unsigned short f2bf(float f) {
  unsigned u = __float_as_uint(f);
  unsigned r = (u + 0x7fffu + ((u >> 16) & 1u)) >> 16;
  return (unsigned short)r;
}
__device__ __forceinline__ float bf2f(unsigned short h) {
  return __uint_as_float(((unsigned)h) << 16);
}

__device__ __forceinline__ void async_ld16(void* lds, const void* g) {
  __builtin_amdgcn_global_load_lds(
      (const __attribute__((address_space(1))) unsigned int*)g,
      (__attribute__((address_space(3))) unsigned int*)lds, 16, 0, 0);
}

// ---------------- CSR build (by dst) ----------------
__global__ void k_zero(int* deg, int n) {
  int i = blockIdx.x*blockDim.x + threadIdx.x;
  if (i < n) deg[i] = 0;
}
__global__ void k_hist(const int* __restrict__ dst, int* deg, int e) {
  int i = blockIdx.x*blockDim.x + threadIdx.x;
  if (i < e) atomicAdd(&deg[dst[i]], 1);
}
__global__ void k_scan(const int* __restrict__ deg, int* row_ptr, int* cursor) {
  __shared__ int sm[1024];
  int t = threadIdx.x;
  const int CH = 20;               // 1024*20 >= 20000
  int base = t*CH;
  int s = 0;
  #pragma unroll
  for (int i = 0; i < CH; ++i) { int idx = base+i; if (idx < NNODES) s += deg[idx]; }
  int val = s;
  sm[t] = s; __syncthreads();
  for (int off = 1; off < 1024; off <<= 1) {
    int add = (t >= off) ? sm[t-off] : 0;
    __syncthreads();
    val += add; sm[t] = val;
    __syncthreads();
  }
  int run = val - s;               // exclusive prefix for this chunk
  for (int i = 0; i < CH; ++i) {
    int idx = base+i;
    if (idx < NNODES) { row_ptr[idx] = run; cursor[idx] = run; run += deg[idx]; }
  }
  if (t == 0) row_ptr[NNODES] = NEDGES;
}
__global__ void k_fill(const int* __restrict__ src, const int* __restrict__ dst,
                       int* cursor, int* srcs_sorted, int e) {
  int i = blockIdx.x*blockDim.x + threadIdx.x;
  if (i < e) { int pos = atomicAdd(&cursor[dst[i]], 1); srcs_sorted[pos] = src[i]; }
}

// ---------------- Wred[k,h] = sum_d Wdst[k, h*D+d] * ar[h,d] ----------------
__global__ void k_wred(const float* __restrict__ Wdst, const float* __restrict__ ar,
                       float* __restrict__ Wred, int K) {
  int wave = threadIdx.x >> 6, lane = threadIdx.x & 63;
  int p = blockIdx.x*4 + wave;          // pair index = k*HEADS + h
  if (p >= K*HEADS) return;
  int k = p >> 2, h = p & 3;
  const float4 wv = *(const float4*)&Wdst[(size_t)k*MCOLS + h*DDIM + lane*4];
  const float4 av = *(const float4*)&ar[h*DDIM + lane*4];
  float s = wv.x*av.x + wv.y*av.y + wv.z*av.z + wv.w*av.w;
  for (int off = 32; off; off >>= 1) s += __shfl_xor(s, off);
  if (lane == 0) Wred[k*HEADS + h] = s;
}

// ---------------- split-bf16 conversion: A (row-major, padded) ----------------
__global__ void k_cvt_a(const float* __restrict__ x, unsigned short* __restrict__ hi,
                        unsigned short* __restrict__ lo, int total, int total_pad) {
  int i = blockIdx.x*blockDim.x + threadIdx.x;
  int idx = i*4;
  if (idx >= total_pad) return;
  float4 v = (idx < total) ? *(const float4*)&x[idx] : make_float4(0.f,0.f,0.f,0.f);
  ushort4 h, l;
  h.x = f2bf(v.x); l.x = f2bf(v.x - bf2f(h.x));
  h.y = f2bf(v.y); l.y = f2bf(v.y - bf2f(h.y));
  h.z = f2bf(v.z); l.z = f2bf(v.z - bf2f(h.z));
  h.w = f2bf(v.w); l.w = f2bf(v.w - bf2f(h.w));
  *(ushort4*)&hi[idx] = h;
  *(ushort4*)&lo[idx] = l;
}

// ---------------- split-bf16 transpose of W: [K][1024] -> [1024][K] ----------------
__global__ __launch_bounds__(256) void k_cvt_w(const float* __restrict__ W,
                                               unsigned short* __restrict__ Th,
                                               unsigned short* __restrict__ Tl, int K) {
  __shared__ float sm[32][33];
  int k0 = blockIdx.y*32, n0 = blockIdx.x*32;
  int t = threadIdx.x;
  int r = t >> 3, c4 = (t & 7)*4;
  *(float4*)&sm[r][c4] = *(const float4*)&W[(size_t)(k0 + r)*MCOLS + n0 + c4];
  __syncthreads();
  ushort4 h, l;
  float x0 = sm[c4+0][r]; h.x = f2bf(x0); l.x = f2bf(x0 - bf2f(h.x));
  float x1 = sm[c4+1][r]; h.y = f2bf(x1); l.y = f2bf(x1 - bf2f(h.y));
  float x2 = sm[c4+2][r]; h.z = f2bf(x2); l.z = f2bf(x2 - bf2f(h.z));
  float x3 = sm[c4+3][r]; h.w = f2bf(x3); l.w = f2bf(x3 - bf2f(h.w));
  size_t o = (size_t)(n0 + r)*K + k0 + c4;
  *(ushort4*)&Th[o] = h;
  *(ushort4*)&Tl[o] = l;
}

// ---------------- MFMA GEMM: C[NPAD,1024] = (Ah+Al)[NPAD,K] @ (Bh+Bl)^T[1024,K]^T ----
// A*: [NPAD][K] bf16 row-major. B*: [1024][K] bf16 row-major (pre-transposed W).
// 3-product split: C = Ah*Bh + Al*Bh + Ah*Bl  (Al*Bl dropped, ~eps^2)
__global__ __launch_bounds__(256) void k_gemm_mfma(
    const unsigned short* __restrict__ Ah, const unsigned short* __restrict__ Al,
    const unsigned short* __restrict__ Bh, const unsigned short* __restrict__ Bl,
    float* __restrict__ C, int K) {
  __shared__ short sAh[128*32], sAl[128*32], sBh[128*32], sBl[128*32];
  const int t = threadIdx.x;
  const int w = t >> 6, l = t & 63;
  const int bm = blockIdx.y, bn = blockIdx.x;
  const int m0 = (w >> 1) * 64, n0 = (w & 1) * 64;

  f32x4 acc[4][4];
  #pragma unroll
  for (int i = 0; i < 4; ++i)
    #pragma unroll
    for (int j = 0; j < 4; ++j) acc[i][j] = (f32x4){0.f, 0.f, 0.f, 0.f};

  // staging: thread t covers tile row (t>>2), k-octet (t&3)*8; 16B per thread per issue
  const int srow = t >> 2, koct = (t & 3) * 8;
  const size_t r64 = (size_t)64 * K;
  const unsigned short* gAh = Ah + (size_t)(bm*128 + srow)*K + koct;
  const unsigned short* gAl = Al + (size_t)(bm*128 + srow)*K + koct;
  const unsigned short* gBh = Bh + (size_t)(bn*128 + srow)*K + koct;
  const unsigned short* gBl = Bl + (size_t)(bn*128 + srow)*K + koct;
  char* lAh = (char*)sAh + w*1024;
  char* lAl = (char*)sAl + w*1024;
  char* lBh = (char*)sBh + w*1024;
  char* lBl = (char*)sBl + w*1024;

  const int fr = l & 15, fq = l >> 4;   // fragment row, quad

  for (int k0 = 0; k0 < K; k0 += 32) {
    async_ld16(lAh,        gAh + k0);
    async_ld16(lAh + 4096, gAh + k0 + r64);
    async_ld16(lAl,        gAl + k0);
    async_ld16(lAl + 4096, gAl + k0 + r64);
    async_ld16(lBh,        gBh + k0);
    async_ld16(lBh + 4096, gBh + k0 + r64);
    async_ld16(lBl,        gBl + k0);
    async_ld16(lBl + 4096, gBl + k0 + r64);
    __syncthreads();

    short8 bhv[4], blv[4];
    #pragma unroll
    for (int nt = 0; nt < 4; ++nt) {
      int off = (n0 + nt*16 + fr)*32 + fq*8;
      bhv[nt] = *(const short8*)&sBh[off];
      blv[nt] = *(const short8*)&sBl[off];
    }
    #pragma unroll
    for (int mt = 0; mt < 4; ++mt) {
      int off = (m0 + mt*16 + fr)*32 + fq*8;
      short8 ah = *(const short8*)&sAh[off];
      short8 al = *(const short8*)&sAl[off];
      #pragma unroll
      for (int nt = 0; nt < 4; ++nt) {
        acc[mt][nt] = __builtin_amdgcn_mfma_f32_16x16x32_bf16(ah, bhv[nt], acc[mt][nt], 0, 0, 0);
        acc[mt][nt] = __builtin_amdgcn_mfma_f32_16x16x32_bf16(al, bhv[nt], acc[mt][nt], 0, 0, 0);
        acc[mt][nt] = __builtin_amdgcn_mfma_f32_16x16x32_bf16(ah, blv[nt], acc[mt][nt], 0, 0, 0);
      }
    }
    __syncthreads();
  }

  // C store: reg r of lane l -> C[m0+mt*16 + fq*4 + r][n0+nt*16 + fr]
  #pragma unroll
  for (int mt = 0; mt < 4; ++mt)
    #pragma unroll
    for (int nt = 0; nt < 4; ++nt) {
      size_t base = (size_t)(bm*128 + m0 + mt*16 + fq*4)*MCOLS + bn*128 + n0 + nt*16 + fr;
      C[base         ] = acc[mt][nt][0];
      C[base + MCOLS ] = acc[mt][nt][1];
      C[base + 2*MCOLS] = acc[mt][nt][2];
      C[base + 3*MCOLS] = acc[mt][nt][3];
    }
}

// ---------------- el[n,h] = sum_d fs[n,h,d]*al[h,d] ----------------
__global__ void k_el(const float* __restrict__ fs, const float* __restrict__ al,
                     float* __restrict__ el) {
  int n = blockIdx.x;
  int h = threadIdx.x >> 6, lane = threadIdx.x & 63;
  const float4 f = *(const float4*)&fs[(size_t)n*MCOLS + h*DDIM + lane*4];
  const float4 a = *(const float4*)&al[h*DDIM + lane*4];
  float s = f.x*a.x + f.y*a.y + f.z*a.z + f.w*a.w;
  for (int off = 32; off; off >>= 1) s += __shfl_xor(s, off);
  if (lane == 0) el[n*HEADS + h] = s;
}

// ---------------- er[n,h] = sum_k hin[n,k]*Wred[k,h] ----------------
__global__ void k_er(const float* __restrict__ hin, const float* __restrict__ Wred,
                     float* __restrict__ er, int K) {
  int n = blockIdx.x;
  int h = threadIdx.x >> 6, lane = threadIdx.x & 63;
  float s = 0.f;
  for (int k = lane; k < K; k += 64) s += hin[(size_t)n*K + k] * Wred[k*HEADS + h];
  for (int off = 32; off; off >>= 1) s += __shfl_xor(s, off);
  if (lane == 0) er[n*HEADS + h] = s;
}

// ---------------- per-dst softmax + weighted aggregation ----------------
__global__ void k_agg(const float* __restrict__ fs, const float* __restrict__ el,
                      const float* __restrict__ er, const int* __restrict__ row_ptr,
                      const int* __restrict__ srcs, const float* __restrict__ bias,
                      float* __restrict__ out, int mode) {
  __shared__ float sm[HEADS*DDIM];
  int n = blockIdx.x;
  int h = threadIdx.x >> 6, lane = threadIdx.x & 63;
  int beg = row_ptr[n], end = row_ptr[n+1];
  float er_nh = er[n*HEADS + h];
  float m = -INFINITY;
  for (int i = beg + lane; i < end; i += 64) {
    int s = srcs[i];
    float e = el[s*HEADS + h] + er_nh;
    e = e >= 0.f ? e : 0.2f*e;
    m = fmaxf(m, e);
  }
  for (int off = 32; off; off >>= 1) m = fmaxf(m, __shfl_xor(m, off));
  float den = 0.f;
  float4 acc = make_float4(0.f, 0.f, 0.f, 0.f);
  const float* fsh = fs + h*DDIM + lane*4;
  for (int i = beg; i < end; ++i) {
    int s = srcs[i];
    float e = el[s*HEADS + h] + er_nh;
    e = e >= 0.f ? e : 0.2f*e;
    float wgt = expf(e - m);
    den += wgt;
    const float4 v = *(const float4*)&fsh[(size_t)s*MCOLS];
    acc.x = fmaf(wgt, v.x, acc.x);
    acc.y = fmaf(wgt, v.y, acc.y);
    acc.z = fmaf(wgt, v.z, acc.z);
    acc.w = fmaf(wgt, v.w, acc.w);
  }
  float inv = den > 0.f ? 1.f/den : 0.f;
  const float4 bv = *(const float4*)&bias[h*DDIM + lane*4];
  acc.x = acc.x*inv + bv.x;
  acc.y = acc.y*inv + bv.y;
  acc.z = acc.z*inv + bv.z;
  acc.w = acc.w*inv + bv.w;
  if (mode == 0) {
    acc.x = fmaxf(acc.x, 0.f); acc.y = fmaxf(acc.y, 0.f);
    acc.z = fmaxf(acc.z, 0.f); acc.w = fmaxf(acc.w, 0.f);
    *(float4*)&out[(size_t)n*MCOLS + h*DDIM + lane*4] = acc;
  } else {
    *(float4*)&sm[h*DDIM + lane*4] = acc;
    __syncthreads();
    int t = threadIdx.x;
    out[(size_t)n*DDIM + t] =
        0.25f*(sm[t] + sm[DDIM + t] + sm[2*DDIM + t] + sm[3*DDIM + t]);
  }
}

extern "C" void kernel_launch(void* const* d_in, const int* in_sizes, int n_in,
                              void* d_out, int out_size, void* d_ws, size_t ws_size,
                              hipStream_t stream) {
  const float* x   = (const float*)d_in[0];
  const int*   src = (const int*)d_in[1];
  const int*   dst = (const int*)d_in[2];
  const float* Wsrc[3] = {(const float*)d_in[3], (const float*)d_in[8],  (const float*)d_in[13]};
  const float* Wdst[3] = {(const float*)d_in[4], (const float*)d_in[9],  (const float*)d_in[14]};
  const float* al[3]   = {(const float*)d_in[5], (const float*)d_in[10], (const float*)d_in[15]};
  const float* ar[3]   = {(const float*)d_in[6], (const float*)d_in[11], (const float*)d_in[16]};
  const float* bb[3]   = {(const float*)d_in[7], (const float*)d_in[12], (const float*)d_in[17]};

  char* ws = (char*)d_ws;
  size_t off = 0;
  auto alloc = [&](size_t bytes) { void* p = ws + off; off += (bytes + 255) & ~255ull; return p; };
  float* bufA = (float*)alloc((size_t)NNODES*MCOLS*4);   // layer activations h
  float* bufB = (float*)alloc((size_t)NPAD*MCOLS*4);     // fs (padded rows for GEMM)
  unsigned short* Ahi = (unsigned short*)alloc((size_t)NPAD*MCOLS*2);
  unsigned short* Alo = (unsigned short*)alloc((size_t)NPAD*MCOLS*2);
  unsigned short* Wth = (unsigned short*)alloc((size_t)MCOLS*MCOLS*2);
  unsigned short* Wtl = (unsigned short*)alloc((size_t)MCOLS*MCOLS*2);
  float* elb  = (float*)alloc((size_t)NNODES*HEADS*4);
  float* erb  = (float*)alloc((size_t)NNODES*HEADS*4);
  float* Wred = (float*)alloc(1024*HEADS*4);
  int* deg     = (int*)alloc((size_t)NNODES*4);
  int* row_ptr = (int*)alloc((size_t)(NNODES+1)*4);
  int* cursor  = (int*)alloc((size_t)NNODES*4);
  int* srcs    = (int*)alloc((size_t)NEDGES*4);
  (void)ws_size; (void)in_sizes; (void)n_in; (void)out_size;

  // CSR build (graph identical across layers)
  k_zero<<<(NNODES+255)/256, 256, 0, stream>>>(deg, NNODES);
  k_hist<<<(NEDGES+255)/256, 256, 0, stream>>>(dst, deg, NEDGES);
  k_scan<<<1, 1024, 0, stream>>>(deg, row_ptr, cursor);
  k_fill<<<(NEDGES+255)/256, 256, 0, stream>>>(src, dst, cursor, srcs, NEDGES);

  const int Fin[3] = {512, 1024, 1024};
  const float* hin = x;
  for (int l = 0; l < 3; ++l) {
    int K = Fin[l];
    int total = NNODES*K, total_pad = NPAD*K;
    k_cvt_a<<<(total_pad/4 + 255)/256, 256, 0, stream>>>(hin, Ahi, Alo, total, total_pad);
    dim3 gw(MCOLS/32, K/32);
    k_cvt_w<<<gw, 256, 0, stream>>>(Wsrc[l], Wth, Wtl, K);
    k_wred<<<K, 256, 0, stream>>>(Wdst[l], ar[l], Wred, K);
    dim3 gg(MCOLS/128, NPAD/128);
    k_gemm_mfma<<<gg, 256, 0, stream>>>(Ahi, Alo, Wth, Wtl, bufB, K);
    k_el<<<NNODES, 256, 0, stream>>>(bufB, al[l], elb);
    k_er<<<NNODES, 256, 0, stream>>>(hin, Wred, erb, K);
    float* outp = (l == 2) ? (float*)d_out : bufA;
    k_agg<<<NNODES, 256, 0, stream>>>(bufB, elb, erb, row_ptr, srcs, bb[l], outp, l == 2 ? 1 : 0);
    hin = bufA;
  }
}

// Round 3
// 1176.781 us; speedup vs baseline: 1.9504x; 1.1959x over previous
//
#include <hip/hip_runtime.h>
#include <hip/hip_bf16.h>
#include <math.h>

#define NNODES 20000
#define NPAD   20096   // 157 * 128
#define NEDGES 320000
#define HEADS  4
#define DDIM   256
#define MCOLS  1024   // H*D

typedef __attribute__((ext_vector_type(8))) short short8;
typedef __attribute__((ext_vector_type(4))) float f32x4;

// bf16 helpers (bit-level, RNE)
__device__ __forceinline__ unsigned short f2bf(float f) {
  unsigned u = __float_as_uint(f);
  unsigned r = (u + 0x7fffu + ((u >> 16) & 1u)) >> 16;
  return (unsigned short)r;
}
__device__ __forceinline__ float bf2f(unsigned short h) {
  return __uint_as_float(((unsigned)h) << 16);
}

__device__ __forceinline__ void async_ld16(void* lds, const void* g) {
  __builtin_amdgcn_global_load_lds(
      (const __attribute__((address_space(1))) unsigned int*)g,
      (__attribute__((address_space(3))) unsigned int*)lds, 16, 0, 0);
}

// ---------------- CSR build (by dst) ----------------
__global__ void k_zero(int* deg, int n) {
  int i = blockIdx.x*blockDim.x + threadIdx.x;
  if (i < n) deg[i] = 0;
}
__global__ void k_hist(const int* __restrict__ dst, int* deg, int e) {
  int i = blockIdx.x*blockDim.x + threadIdx.x;
  if (i < e) atomicAdd(&deg[dst[i]], 1);
}
__global__ void k_scan(const int* __restrict__ deg, int* row_ptr, int* cursor) {
  __shared__ int sm[1024];
  int t = threadIdx.x;
  const int CH = 20;
  int base = t*CH;
  int s = 0;
  #pragma unroll
  for (int i = 0; i < CH; ++i) { int idx = base+i; if (idx < NNODES) s += deg[idx]; }
  int val = s;
  sm[t] = s; __syncthreads();
  for (int off = 1; off < 1024; off <<= 1) {
    int add = (t >= off) ? sm[t-off] : 0;
    __syncthreads();
    val += add; sm[t] = val;
    __syncthreads();
  }
  int run = val - s;
  for (int i = 0; i < CH; ++i) {
    int idx = base+i;
    if (idx < NNODES) { row_ptr[idx] = run; cursor[idx] = run; run += deg[idx]; }
  }
  if (t == 0) row_ptr[NNODES] = NEDGES;
}
__global__ void k_fill(const int* __restrict__ src, const int* __restrict__ dst,
                       int* cursor, int* srcs_sorted, int e) {
  int i = blockIdx.x*blockDim.x + threadIdx.x;
  if (i < e) { int pos = atomicAdd(&cursor[dst[i]], 1); srcs_sorted[pos] = src[i]; }
}

// ---------------- Wred[k,h] = sum_d Wdst[k, h*D+d] * ar[h,d] ----------------
__global__ void k_wred(const float* __restrict__ Wdst, const float* __restrict__ ar,
                       float* __restrict__ Wred, int K) {
  int wave = threadIdx.x >> 6, lane = threadIdx.x & 63;
  int p = blockIdx.x*4 + wave;
  if (p >= K*HEADS) return;
  int k = p >> 2, h = p & 3;
  const float4 wv = *(const float4*)&Wdst[(size_t)k*MCOLS + h*DDIM + lane*4];
  const float4 av = *(const float4*)&ar[h*DDIM + lane*4];
  float s = wv.x*av.x + wv.y*av.y + wv.z*av.z + wv.w*av.w;
  for (int off = 32; off; off >>= 1) s += __shfl_xor(s, off);
  if (lane == 0) Wred[k*HEADS + h] = s;
}

// ---------------- split-bf16 conversion: A (row-major, padded) ----------------
__global__ void k_cvt_a(const float* __restrict__ x, unsigned short* __restrict__ hi,
                        unsigned short* __restrict__ lo, int total, int total_pad) {
  int i = blockIdx.x*blockDim.x + threadIdx.x;
  int idx = i*4;
  if (idx >= total_pad) return;
  float4 v = (idx < total) ? *(const float4*)&x[idx] : make_float4(0.f,0.f,0.f,0.f);
  ushort4 h, l;
  h.x = f2bf(v.x); l.x = f2bf(v.x - bf2f(h.x));
  h.y = f2bf(v.y); l.y = f2bf(v.y - bf2f(h.y));
  h.z = f2bf(v.z); l.z = f2bf(v.z - bf2f(h.z));
  h.w = f2bf(v.w); l.w = f2bf(v.w - bf2f(h.w));
  *(ushort4*)&hi[idx] = h;
  *(ushort4*)&lo[idx] = l;
}

// ---------------- split-bf16 transpose of W: [K][1024] -> [1024][K] ----------------
__global__ __launch_bounds__(256) void k_cvt_w(const float* __restrict__ W,
                                               unsigned short* __restrict__ Th,
                                               unsigned short* __restrict__ Tl, int K) {
  __shared__ float sm[32][33];
  int k0 = blockIdx.y*32, n0 = blockIdx.x*32;
  int t = threadIdx.x;
  int r = t >> 3, c4 = (t & 7)*4;
  *(float4*)&sm[r][c4] = *(const float4*)&W[(size_t)(k0 + r)*MCOLS + n0 + c4];
  __syncthreads();
  ushort4 h, l;
  float x0 = sm[c4+0][r]; h.x = f2bf(x0); l.x = f2bf(x0 - bf2f(h.x));
  float x1 = sm[c4+1][r]; h.y = f2bf(x1); l.y = f2bf(x1 - bf2f(h.y));
  float x2 = sm[c4+2][r]; h.z = f2bf(x2); l.z = f2bf(x2 - bf2f(h.z));
  float x3 = sm[c4+3][r]; h.w = f2bf(x3); l.w = f2bf(x3 - bf2f(h.w));
  size_t o = (size_t)(n0 + r)*K + k0 + c4;
  *(ushort4*)&Th[o] = h;
  *(ushort4*)&Tl[o] = l;
}

// ---------------- MFMA GEMM (split-bf16, 3 products) ----------------
__global__ __launch_bounds__(256) void k_gemm_mfma(
    const unsigned short* __restrict__ Ah, const unsigned short* __restrict__ Al,
    const unsigned short* __restrict__ Bh, const unsigned short* __restrict__ Bl,
    float* __restrict__ C, int K) {
  __shared__ short sAh[128*32], sAl[128*32], sBh[128*32], sBl[128*32];
  const int t = threadIdx.x;
  const int w = t >> 6, l = t & 63;
  const int bm = blockIdx.y, bn = blockIdx.x;
  const int m0 = (w >> 1) * 64, n0 = (w & 1) * 64;

  f32x4 acc[4][4];
  #pragma unroll
  for (int i = 0; i < 4; ++i)
    #pragma unroll
    for (int j = 0; j < 4; ++j) acc[i][j] = (f32x4){0.f, 0.f, 0.f, 0.f};

  const int srow = t >> 2, koct = (t & 3) * 8;
  const size_t r64 = (size_t)64 * K;
  const unsigned short* gAh = Ah + (size_t)(bm*128 + srow)*K + koct;
  const unsigned short* gAl = Al + (size_t)(bm*128 + srow)*K + koct;
  const unsigned short* gBh = Bh + (size_t)(bn*128 + srow)*K + koct;
  const unsigned short* gBl = Bl + (size_t)(bn*128 + srow)*K + koct;
  char* lAh = (char*)sAh + w*1024;
  char* lAl = (char*)sAl + w*1024;
  char* lBh = (char*)sBh + w*1024;
  char* lBl = (char*)sBl + w*1024;

  const int fr = l & 15, fq = l >> 4;

  for (int k0 = 0; k0 < K; k0 += 32) {
    async_ld16(lAh,        gAh + k0);
    async_ld16(lAh + 4096, gAh + k0 + r64);
    async_ld16(lAl,        gAl + k0);
    async_ld16(lAl + 4096, gAl + k0 + r64);
    async_ld16(lBh,        gBh + k0);
    async_ld16(lBh + 4096, gBh + k0 + r64);
    async_ld16(lBl,        gBl + k0);
    async_ld16(lBl + 4096, gBl + k0 + r64);
    __syncthreads();

    short8 bhv[4], blv[4];
    #pragma unroll
    for (int nt = 0; nt < 4; ++nt) {
      int off = (n0 + nt*16 + fr)*32 + fq*8;
      bhv[nt] = *(const short8*)&sBh[off];
      blv[nt] = *(const short8*)&sBl[off];
    }
    #pragma unroll
    for (int mt = 0; mt < 4; ++mt) {
      int off = (m0 + mt*16 + fr)*32 + fq*8;
      short8 ah = *(const short8*)&sAh[off];
      short8 al = *(const short8*)&sAl[off];
      #pragma unroll
      for (int nt = 0; nt < 4; ++nt) {
        acc[mt][nt] = __builtin_amdgcn_mfma_f32_16x16x32_bf16(ah, bhv[nt], acc[mt][nt], 0, 0, 0);
        acc[mt][nt] = __builtin_amdgcn_mfma_f32_16x16x32_bf16(al, bhv[nt], acc[mt][nt], 0, 0, 0);
        acc[mt][nt] = __builtin_amdgcn_mfma_f32_16x16x32_bf16(ah, blv[nt], acc[mt][nt], 0, 0, 0);
      }
    }
    __syncthreads();
  }

  #pragma unroll
  for (int mt = 0; mt < 4; ++mt)
    #pragma unroll
    for (int nt = 0; nt < 4; ++nt) {
      size_t base = (size_t)(bm*128 + m0 + mt*16 + fq*4)*MCOLS + bn*128 + n0 + nt*16 + fr;
      C[base          ] = acc[mt][nt][0];
      C[base + MCOLS  ] = acc[mt][nt][1];
      C[base + 2*MCOLS] = acc[mt][nt][2];
      C[base + 3*MCOLS] = acc[mt][nt][3];
    }
}

// ---------------- el[n,h] = sum_d fs[n,h,d]*al[h,d] ----------------
__global__ void k_el(const float* __restrict__ fs, const float* __restrict__ al,
                     float* __restrict__ el) {
  int n = blockIdx.x;
  int h = threadIdx.x >> 6, lane = threadIdx.x & 63;
  const float4 f = *(const float4*)&fs[(size_t)n*MCOLS + h*DDIM + lane*4];
  const float4 a = *(const float4*)&al[h*DDIM + lane*4];
  float s = f.x*a.x + f.y*a.y + f.z*a.z + f.w*a.w;
  for (int off = 32; off; off >>= 1) s += __shfl_xor(s, off);
  if (lane == 0) el[n*HEADS + h] = s;
}

// ---------------- er[n,h] = sum_k hin[n,k]*Wred[k,h]  (layer 0 only) ----------------
__global__ void k_er(const float* __restrict__ hin, const float* __restrict__ Wred,
                     float* __restrict__ er, int K) {
  int n = blockIdx.x;
  int h = threadIdx.x >> 6, lane = threadIdx.x & 63;
  float s = 0.f;
  for (int k = lane; k < K; k += 64) s += hin[(size_t)n*K + k] * Wred[k*HEADS + h];
  for (int off = 32; off; off >>= 1) s += __shfl_xor(s, off);
  if (lane == 0) er[n*HEADS + h] = s;
}

// ---------------- fused aggregation (layers 0,1) ----------------
// out = relu(softmax-agg + b); emits split-bf16 (next GEMM A) + er_next (via WredN).
// Launched with NPAD blocks; pad blocks just zero their A rows.
__global__ __launch_bounds__(256) void k_agg_f(
    const float* __restrict__ fs, const float* __restrict__ el,
    const float* __restrict__ er, const int* __restrict__ row_ptr,
    const int* __restrict__ srcs, const float* __restrict__ bias,
    const float* __restrict__ WredN,
    unsigned short* __restrict__ Ahi, unsigned short* __restrict__ Alo,
    float* __restrict__ er_next) {
  __shared__ float er_sm[HEADS][HEADS];
  int n = blockIdx.x;
  int h = threadIdx.x >> 6, lane = threadIdx.x & 63;
  int k0 = h*DDIM + lane*4;                 // this thread's 4 output dims
  if (n >= NNODES) {                        // zero the GEMM pad rows
    ushort4 z = {0,0,0,0};
    *(ushort4*)&Ahi[(size_t)n*MCOLS + k0] = z;
    *(ushort4*)&Alo[(size_t)n*MCOLS + k0] = z;
    return;
  }
  int beg = row_ptr[n], end = row_ptr[n+1];
  float er_nh = er[n*HEADS + h];
  // pass 1: segment max
  float m = -INFINITY;
  for (int i = beg + lane; i < end; i += 64) {
    int s = srcs[i];
    float e = el[s*HEADS + h] + er_nh;
    e = e >= 0.f ? e : 0.2f*e;
    m = fmaxf(m, e);
  }
  for (int off = 32; off; off >>= 1) m = fmaxf(m, __shfl_xor(m, off));
  // pass 2: unrolled x4 for MLP
  float den = 0.f;
  float4 acc = make_float4(0.f, 0.f, 0.f, 0.f);
  const float* fsh = fs + h*DDIM + lane*4;
  int i = beg;
  for (; i + 3 < end; i += 4) {
    int s0 = srcs[i], s1 = srcs[i+1], s2 = srcs[i+2], s3 = srcs[i+3];
    float e0 = el[s0*HEADS + h] + er_nh;
    float e1 = el[s1*HEADS + h] + er_nh;
    float e2 = el[s2*HEADS + h] + er_nh;
    float e3 = el[s3*HEADS + h] + er_nh;
    const float4 v0 = *(const float4*)&fsh[(size_t)s0*MCOLS];
    const float4 v1 = *(const float4*)&fsh[(size_t)s1*MCOLS];
    const float4 v2 = *(const float4*)&fsh[(size_t)s2*MCOLS];
    const float4 v3 = *(const float4*)&fsh[(size_t)s3*MCOLS];
    e0 = e0 >= 0.f ? e0 : 0.2f*e0;  float w0 = expf(e0 - m);
    e1 = e1 >= 0.f ? e1 : 0.2f*e1;  float w1 = expf(e1 - m);
    e2 = e2 >= 0.f ? e2 : 0.2f*e2;  float w2 = expf(e2 - m);
    e3 = e3 >= 0.f ? e3 : 0.2f*e3;  float w3 = expf(e3 - m);
    den += (w0 + w1) + (w2 + w3);
    acc.x = fmaf(w0, v0.x, fmaf(w1, v1.x, fmaf(w2, v2.x, fmaf(w3, v3.x, acc.x))));
    acc.y = fmaf(w0, v0.y, fmaf(w1, v1.y, fmaf(w2, v2.y, fmaf(w3, v3.y, acc.y))));
    acc.z = fmaf(w0, v0.z, fmaf(w1, v1.z, fmaf(w2, v2.z, fmaf(w3, v3.z, acc.z))));
    acc.w = fmaf(w0, v0.w, fmaf(w1, v1.w, fmaf(w2, v2.w, fmaf(w3, v3.w, acc.w))));
  }
  for (; i < end; ++i) {
    int s = srcs[i];
    float e = el[s*HEADS + h] + er_nh;
    e = e >= 0.f ? e : 0.2f*e;
    float wgt = expf(e - m);
    den += wgt;
    const float4 v = *(const float4*)&fsh[(size_t)s*MCOLS];
    acc.x = fmaf(wgt, v.x, acc.x);
    acc.y = fmaf(wgt, v.y, acc.y);
    acc.z = fmaf(wgt, v.z, acc.z);
    acc.w = fmaf(wgt, v.w, acc.w);
  }
  float inv = den > 0.f ? 1.f/den : 0.f;
  const float4 bv = *(const float4*)&bias[k0];
  float4 o;
  o.x = fmaxf(acc.x*inv + bv.x, 0.f);
  o.y = fmaxf(acc.y*inv + bv.y, 0.f);
  o.z = fmaxf(acc.z*inv + bv.z, 0.f);
  o.w = fmaxf(acc.w*inv + bv.w, 0.f);
  // split-bf16 emit (next layer GEMM A)
  ushort4 hv, lv;
  hv.x = f2bf(o.x); lv.x = f2bf(o.x - bf2f(hv.x));
  hv.y = f2bf(o.y); lv.y = f2bf(o.y - bf2f(hv.y));
  hv.z = f2bf(o.z); lv.z = f2bf(o.z - bf2f(hv.z));
  hv.w = f2bf(o.w); lv.w = f2bf(o.w - bf2f(hv.w));
  *(ushort4*)&Ahi[(size_t)n*MCOLS + k0] = hv;
  *(ushort4*)&Alo[(size_t)n*MCOLS + k0] = lv;
  // er_next[n,h2] = sum_k o[k] * WredN[k,h2]
  const float4 q0 = *(const float4*)&WredN[(k0+0)*HEADS];
  const float4 q1 = *(const float4*)&WredN[(k0+1)*HEADS];
  const float4 q2 = *(const float4*)&WredN[(k0+2)*HEADS];
  const float4 q3 = *(const float4*)&WredN[(k0+3)*HEADS];
  float p0 = o.x*q0.x + o.y*q1.x + o.z*q2.x + o.w*q3.x;
  float p1 = o.x*q0.y + o.y*q1.y + o.z*q2.y + o.w*q3.y;
  float p2 = o.x*q0.z + o.y*q1.z + o.z*q2.z + o.w*q3.z;
  float p3 = o.x*q0.w + o.y*q1.w + o.z*q2.w + o.w*q3.w;
  for (int off = 32; off; off >>= 1) {
    p0 += __shfl_xor(p0, off);
    p1 += __shfl_xor(p1, off);
    p2 += __shfl_xor(p2, off);
    p3 += __shfl_xor(p3, off);
  }
  if (lane == 0) {
    er_sm[h][0] = p0; er_sm[h][1] = p1; er_sm[h][2] = p2; er_sm[h][3] = p3;
  }
  __syncthreads();
  if (threadIdx.x < HEADS) {
    int t = threadIdx.x;
    er_next[n*HEADS + t] = (er_sm[0][t] + er_sm[1][t]) + (er_sm[2][t] + er_sm[3][t]);
  }
}

// ---------------- final aggregation (layer 2): mean over heads ----------------
__global__ __launch_bounds__(256) void k_agg_out(
    const float* __restrict__ fs, const float* __restrict__ el,
    const float* __restrict__ er, const int* __restrict__ row_ptr,
    const int* __restrict__ srcs, const float* __restrict__ bias,
    float* __restrict__ out) {
  __shared__ float sm[HEADS*DDIM];
  int n = blockIdx.x;
  int h = threadIdx.x >> 6, lane = threadIdx.x & 63;
  int beg = row_ptr[n], end = row_ptr[n+1];
  float er_nh = er[n*HEADS + h];
  float m = -INFINITY;
  for (int i = beg + lane; i < end; i += 64) {
    int s = srcs[i];
    float e = el[s*HEADS + h] + er_nh;
    e = e >= 0.f ? e : 0.2f*e;
    m = fmaxf(m, e);
  }
  for (int off = 32; off; off >>= 1) m = fmaxf(m, __shfl_xor(m, off));
  float den = 0.f;
  float4 acc = make_float4(0.f, 0.f, 0.f, 0.f);
  const float* fsh = fs + h*DDIM + lane*4;
  int i = beg;
  for (; i + 3 < end; i += 4) {
    int s0 = srcs[i], s1 = srcs[i+1], s2 = srcs[i+2], s3 = srcs[i+3];
    float e0 = el[s0*HEADS + h] + er_nh;
    float e1 = el[s1*HEADS + h] + er_nh;
    float e2 = el[s2*HEADS + h] + er_nh;
    float e3 = el[s3*HEADS + h] + er_nh;
    const float4 v0 = *(const float4*)&fsh[(size_t)s0*MCOLS];
    const float4 v1 = *(const float4*)&fsh[(size_t)s1*MCOLS];
    const float4 v2 = *(const float4*)&fsh[(size_t)s2*MCOLS];
    const float4 v3 = *(const float4*)&fsh[(size_t)s3*MCOLS];
    e0 = e0 >= 0.f ? e0 : 0.2f*e0;  float w0 = expf(e0 - m);
    e1 = e1 >= 0.f ? e1 : 0.2f*e1;  float w1 = expf(e1 - m);
    e2 = e2 >= 0.f ? e2 : 0.2f*e2;  float w2 = expf(e2 - m);
    e3 = e3 >= 0.f ? e3 : 0.2f*e3;  float w3 = expf(e3 - m);
    den += (w0 + w1) + (w2 + w3);
    acc.x = fmaf(w0, v0.x, fmaf(w1, v1.x, fmaf(w2, v2.x, fmaf(w3, v3.x, acc.x))));
    acc.y = fmaf(w0, v0.y, fmaf(w1, v1.y, fmaf(w2, v2.y, fmaf(w3, v3.y, acc.y))));
    acc.z = fmaf(w0, v0.z, fmaf(w1, v1.z, fmaf(w2, v2.z, fmaf(w3, v3.z, acc.z))));
    acc.w = fmaf(w0, v0.w, fmaf(w1, v1.w, fmaf(w2, v2.w, fmaf(w3, v3.w, acc.w))));
  }
  for (; i < end; ++i) {
    int s = srcs[i];
    float e = el[s*HEADS + h] + er_nh;
    e = e >= 0.f ? e : 0.2f*e;
    float wgt = expf(e - m);
    den += wgt;
    const float4 v = *(const float4*)&fsh[(size_t)s*MCOLS];
    acc.x = fmaf(wgt, v.x, acc.x);
    acc.y = fmaf(wgt, v.y, acc.y);
    acc.z = fmaf(wgt, v.z, acc.z);
    acc.w = fmaf(wgt, v.w, acc.w);
  }
  float inv = den > 0.f ? 1.f/den : 0.f;
  const float4 bv = *(const float4*)&bias[h*DDIM + lane*4];
  acc.x = acc.x*inv + bv.x;
  acc.y = acc.y*inv + bv.y;
  acc.z = acc.z*inv + bv.z;
  acc.w = acc.w*inv + bv.w;
  *(float4*)&sm[h*DDIM + lane*4] = acc;
  __syncthreads();
  int t = threadIdx.x;
  out[(size_t)n*DDIM + t] =
      0.25f*((sm[t] + sm[DDIM + t]) + (sm[2*DDIM + t] + sm[3*DDIM + t]));
}

extern "C" void kernel_launch(void* const* d_in, const int* in_sizes, int n_in,
                              void* d_out, int out_size, void* d_ws, size_t ws_size,
                              hipStream_t stream) {
  const float* x   = (const float*)d_in[0];
  const int*   src = (const int*)d_in[1];
  const int*   dst = (const int*)d_in[2];
  const float* Wsrc[3] = {(const float*)d_in[3], (const float*)d_in[8],  (const float*)d_in[13]};
  const float* Wdst[3] = {(const float*)d_in[4], (const float*)d_in[9],  (const float*)d_in[14]};
  const float* al[3]   = {(const float*)d_in[5], (const float*)d_in[10], (const float*)d_in[15]};
  const float* ar[3]   = {(const float*)d_in[6], (const float*)d_in[11], (const float*)d_in[16]};
  const float* bb[3]   = {(const float*)d_in[7], (const float*)d_in[12], (const float*)d_in[17]};

  char* ws = (char*)d_ws;
  size_t off = 0;
  auto alloc = [&](size_t bytes) { void* p = ws + off; off += (bytes + 255) & ~255ull; return p; };
  float* bufB = (float*)alloc((size_t)NPAD*MCOLS*4);     // fs (GEMM output)
  unsigned short* Ahi = (unsigned short*)alloc((size_t)NPAD*MCOLS*2);
  unsigned short* Alo = (unsigned short*)alloc((size_t)NPAD*MCOLS*2);
  unsigned short* Wth = (unsigned short*)alloc((size_t)MCOLS*MCOLS*2);
  unsigned short* Wtl = (unsigned short*)alloc((size_t)MCOLS*MCOLS*2);
  float* elb  = (float*)alloc((size_t)NNODES*HEADS*4);
  float* erA  = (float*)alloc((size_t)NNODES*HEADS*4);
  float* erB  = (float*)alloc((size_t)NNODES*HEADS*4);
  float* WredB[3];
  WredB[0] = (float*)alloc(1024*HEADS*4);
  WredB[1] = (float*)alloc(1024*HEADS*4);
  WredB[2] = (float*)alloc(1024*HEADS*4);
  int* deg     = (int*)alloc((size_t)NNODES*4);
  int* row_ptr = (int*)alloc((size_t)(NNODES+1)*4);
  int* cursor  = (int*)alloc((size_t)NNODES*4);
  int* srcs    = (int*)alloc((size_t)NEDGES*4);
  (void)ws_size; (void)in_sizes; (void)n_in; (void)out_size;

  // CSR build (graph identical across layers)
  k_zero<<<(NNODES+255)/256, 256, 0, stream>>>(deg, NNODES);
  k_hist<<<(NEDGES+255)/256, 256, 0, stream>>>(dst, deg, NEDGES);
  k_scan<<<1, 1024, 0, stream>>>(deg, row_ptr, cursor);
  k_fill<<<(NEDGES+255)/256, 256, 0, stream>>>(src, dst, cursor, srcs, NEDGES);

  const int Fin[3] = {512, 1024, 1024};
  for (int l = 0; l < 3; ++l)
    k_wred<<<Fin[l], 256, 0, stream>>>(Wdst[l], ar[l], WredB[l], Fin[l]);

  // layer 0 input prep
  k_cvt_a<<<(NPAD*512/4 + 255)/256, 256, 0, stream>>>(x, Ahi, Alo, NNODES*512, NPAD*512);
  k_er<<<NNODES, 256, 0, stream>>>(x, WredB[0], erA, 512);

  float* er_cur = erA;
  float* er_nxt = erB;
  for (int l = 0; l < 3; ++l) {
    int K = Fin[l];
    dim3 gw(MCOLS/32, K/32);
    k_cvt_w<<<gw, 256, 0, stream>>>(Wsrc[l], Wth, Wtl, K);
    dim3 gg(MCOLS/128, NPAD/128);
    k_gemm_mfma<<<gg, 256, 0, stream>>>(Ahi, Alo, Wth, Wtl, bufB, K);
    k_el<<<NNODES, 256, 0, stream>>>(bufB, al[l], elb);
    if (l < 2) {
      k_agg_f<<<NPAD, 256, 0, stream>>>(bufB, elb, er_cur, row_ptr, srcs, bb[l],
                                        WredB[l+1], Ahi, Alo, er_nxt);
      float* tmp = er_cur; er_cur = er_nxt; er_nxt = tmp;
    } else {
      k_agg_out<<<NNODES, 256, 0, stream>>>(bufB, elb, er_cur, row_ptr, srcs, bb[l],
                                            (float*)d_out);
    }
  }
}

// Round 4
// 991.651 us; speedup vs baseline: 2.3145x; 1.1867x over previous
//
#include <hip/hip_runtime.h>
#include <hip/hip_bf16.h>
#include <math.h>

#define NNODES 20000
#define NPAD   20096   // 157 * 128
#define NEDGES 320000
#define HEADS  4
#define DDIM   256
#define MCOLS  1024   // H*D

typedef __attribute__((ext_vector_type(8))) short short8;
typedef __attribute__((ext_vector_type(4))) float f32x4;

// bf16 helpers (bit-level, RNE)
__device__ __forceinline__ unsigned short f2bf(float f) {
  unsigned u = __float_as_uint(f);
  unsigned r = (u + 0x7fffu + ((u >> 16) & 1u)) >> 16;
  return (unsigned short)r;
}
__device__ __forceinline__ float bf2f(unsigned short h) {
  return __uint_as_float(((unsigned)h) << 16);
}

__device__ __forceinline__ void async_ld16(void* lds, const void* g) {
  __builtin_amdgcn_global_load_lds(
      (const __attribute__((address_space(1))) unsigned int*)g,
      (__attribute__((address_space(3))) unsigned int*)lds, 16, 0, 0);
}

// ---------------- CSR build (by dst) ----------------
__global__ void k_zero(int* deg, int n) {
  int i = blockIdx.x*blockDim.x + threadIdx.x;
  if (i < n) deg[i] = 0;
}
__global__ void k_hist(const int* __restrict__ dst, int* deg, int e) {
  int i = blockIdx.x*blockDim.x + threadIdx.x;
  if (i < e) atomicAdd(&deg[dst[i]], 1);
}
__global__ void k_scan(const int* __restrict__ deg, int* row_ptr, int* cursor) {
  __shared__ int sm[1024];
  int t = threadIdx.x;
  const int CH = 20;
  int base = t*CH;
  int s = 0;
  #pragma unroll
  for (int i = 0; i < CH; ++i) { int idx = base+i; if (idx < NNODES) s += deg[idx]; }
  int val = s;
  sm[t] = s; __syncthreads();
  for (int off = 1; off < 1024; off <<= 1) {
    int add = (t >= off) ? sm[t-off] : 0;
    __syncthreads();
    val += add; sm[t] = val;
    __syncthreads();
  }
  int run = val - s;
  for (int i = 0; i < CH; ++i) {
    int idx = base+i;
    if (idx < NNODES) { row_ptr[idx] = run; cursor[idx] = run; run += deg[idx]; }
  }
  if (t == 0) row_ptr[NNODES] = NEDGES;
}
__global__ void k_fill(const int* __restrict__ src, const int* __restrict__ dst,
                       int* cursor, int* srcs_sorted, int e) {
  int i = blockIdx.x*blockDim.x + threadIdx.x;
  if (i < e) { int pos = atomicAdd(&cursor[dst[i]], 1); srcs_sorted[pos] = src[i]; }
}

// ---------------- fold: F[k,h] = sum_d W[k, h*D+d] * v[h,d] ----------------
__global__ void k_fold(const float* __restrict__ W, const float* __restrict__ v,
                       float* __restrict__ F, int K) {
  int wave = threadIdx.x >> 6, lane = threadIdx.x & 63;
  int p = blockIdx.x*4 + wave;
  if (p >= K*HEADS) return;
  int k = p >> 2, h = p & 3;
  const float4 wv = *(const float4*)&W[(size_t)k*MCOLS + h*DDIM + lane*4];
  const float4 av = *(const float4*)&v[h*DDIM + lane*4];
  float s = wv.x*av.x + wv.y*av.y + wv.z*av.z + wv.w*av.w;
  for (int off = 32; off; off >>= 1) s += __shfl_xor(s, off);
  if (lane == 0) F[k*HEADS + h] = s;
}

// ---------------- split-bf16 conversion: A (row-major, padded) ----------------
__global__ void k_cvt_a(const float* __restrict__ x, unsigned short* __restrict__ hi,
                        unsigned short* __restrict__ lo, int total, int total_pad) {
  int i = blockIdx.x*blockDim.x + threadIdx.x;
  int idx = i*4;
  if (idx >= total_pad) return;
  float4 v = (idx < total) ? *(const float4*)&x[idx] : make_float4(0.f,0.f,0.f,0.f);
  ushort4 h, l;
  h.x = f2bf(v.x); l.x = f2bf(v.x - bf2f(h.x));
  h.y = f2bf(v.y); l.y = f2bf(v.y - bf2f(h.y));
  h.z = f2bf(v.z); l.z = f2bf(v.z - bf2f(h.z));
  h.w = f2bf(v.w); l.w = f2bf(v.w - bf2f(h.w));
  *(ushort4*)&hi[idx] = h;
  *(ushort4*)&lo[idx] = l;
}

// ---------------- split-bf16 transpose of W: [K][1024] -> [1024][K] ----------------
__global__ __launch_bounds__(256) void k_cvt_w(const float* __restrict__ W,
                                               unsigned short* __restrict__ Th,
                                               unsigned short* __restrict__ Tl, int K) {
  __shared__ float sm[32][33];
  int k0 = blockIdx.y*32, n0 = blockIdx.x*32;
  int t = threadIdx.x;
  int r = t >> 3, c4 = (t & 7)*4;
  *(float4*)&sm[r][c4] = *(const float4*)&W[(size_t)(k0 + r)*MCOLS + n0 + c4];
  __syncthreads();
  ushort4 h, l;
  float x0 = sm[c4+0][r]; h.x = f2bf(x0); l.x = f2bf(x0 - bf2f(h.x));
  float x1 = sm[c4+1][r]; h.y = f2bf(x1); l.y = f2bf(x1 - bf2f(h.y));
  float x2 = sm[c4+2][r]; h.z = f2bf(x2); l.z = f2bf(x2 - bf2f(h.z));
  float x3 = sm[c4+3][r]; h.w = f2bf(x3); l.w = f2bf(x3 - bf2f(h.w));
  size_t o = (size_t)(n0 + r)*K + k0 + c4;
  *(ushort4*)&Th[o] = h;
  *(ushort4*)&Tl[o] = l;
}

// ---------------- el0/er0[n,h] = sum_k x[n,k]*{Wal0,Wred0}[k,h] ----------------
__global__ void k_eler0(const float* __restrict__ x, const float* __restrict__ Wal,
                        const float* __restrict__ Wred,
                        float* __restrict__ el, float* __restrict__ er) {
  int n = blockIdx.x;
  int h = threadIdx.x >> 6, lane = threadIdx.x & 63;
  float sl = 0.f, sr = 0.f;
  for (int k = lane; k < 512; k += 64) {
    float xv = x[(size_t)n*512 + k];
    sl = fmaf(xv, Wal[k*HEADS + h], sl);
    sr = fmaf(xv, Wred[k*HEADS + h], sr);
  }
  for (int off = 32; off; off >>= 1) { sl += __shfl_xor(sl, off); sr += __shfl_xor(sr, off); }
  if (lane == 0) { el[n*HEADS + h] = sl; er[n*HEADS + h] = sr; }
}

// ---------------- MFMA GEMM (split-bf16, 3 products) ----------------
// mode 0: write fp32 to Cf.  mode 1: write bf16(RNE) to Fh.
__global__ __launch_bounds__(256) void k_gemm_mfma(
    const unsigned short* __restrict__ Ah, const unsigned short* __restrict__ Al,
    const unsigned short* __restrict__ Bh, const unsigned short* __restrict__ Bl,
    float* __restrict__ Cf, unsigned short* __restrict__ Fh, int K, int bf16mode) {
  __shared__ short sAh[128*32], sAl[128*32], sBh[128*32], sBl[128*32];
  const int t = threadIdx.x;
  const int w = t >> 6, l = t & 63;
  const int bm = blockIdx.y, bn = blockIdx.x;
  const int m0 = (w >> 1) * 64, n0 = (w & 1) * 64;

  f32x4 acc[4][4];
  #pragma unroll
  for (int i = 0; i < 4; ++i)
    #pragma unroll
    for (int j = 0; j < 4; ++j) acc[i][j] = (f32x4){0.f, 0.f, 0.f, 0.f};

  const int srow = t >> 2, koct = (t & 3) * 8;
  const size_t r64 = (size_t)64 * K;
  const unsigned short* gAh = Ah + (size_t)(bm*128 + srow)*K + koct;
  const unsigned short* gAl = Al + (size_t)(bm*128 + srow)*K + koct;
  const unsigned short* gBh = Bh + (size_t)(bn*128 + srow)*K + koct;
  const unsigned short* gBl = Bl + (size_t)(bn*128 + srow)*K + koct;
  char* lAh = (char*)sAh + w*1024;
  char* lAl = (char*)sAl + w*1024;
  char* lBh = (char*)sBh + w*1024;
  char* lBl = (char*)sBl + w*1024;

  const int fr = l & 15, fq = l >> 4;

  for (int k0 = 0; k0 < K; k0 += 32) {
    async_ld16(lAh,        gAh + k0);
    async_ld16(lAh + 4096, gAh + k0 + r64);
    async_ld16(lAl,        gAl + k0);
    async_ld16(lAl + 4096, gAl + k0 + r64);
    async_ld16(lBh,        gBh + k0);
    async_ld16(lBh + 4096, gBh + k0 + r64);
    async_ld16(lBl,        gBl + k0);
    async_ld16(lBl + 4096, gBl + k0 + r64);
    __syncthreads();

    short8 bhv[4], blv[4];
    #pragma unroll
    for (int nt = 0; nt < 4; ++nt) {
      int off = (n0 + nt*16 + fr)*32 + fq*8;
      bhv[nt] = *(const short8*)&sBh[off];
      blv[nt] = *(const short8*)&sBl[off];
    }
    #pragma unroll
    for (int mt = 0; mt < 4; ++mt) {
      int off = (m0 + mt*16 + fr)*32 + fq*8;
      short8 ah = *(const short8*)&sAh[off];
      short8 al = *(const short8*)&sAl[off];
      #pragma unroll
      for (int nt = 0; nt < 4; ++nt) {
        acc[mt][nt] = __builtin_amdgcn_mfma_f32_16x16x32_bf16(ah, bhv[nt], acc[mt][nt], 0, 0, 0);
        acc[mt][nt] = __builtin_amdgcn_mfma_f32_16x16x32_bf16(al, bhv[nt], acc[mt][nt], 0, 0, 0);
        acc[mt][nt] = __builtin_amdgcn_mfma_f32_16x16x32_bf16(ah, blv[nt], acc[mt][nt], 0, 0, 0);
      }
    }
    __syncthreads();
  }

  if (bf16mode) {
    #pragma unroll
    for (int mt = 0; mt < 4; ++mt)
      #pragma unroll
      for (int nt = 0; nt < 4; ++nt) {
        size_t base = (size_t)(bm*128 + m0 + mt*16 + fq*4)*MCOLS + bn*128 + n0 + nt*16 + fr;
        Fh[base          ] = f2bf(acc[mt][nt][0]);
        Fh[base + MCOLS  ] = f2bf(acc[mt][nt][1]);
        Fh[base + 2*MCOLS] = f2bf(acc[mt][nt][2]);
        Fh[base + 3*MCOLS] = f2bf(acc[mt][nt][3]);
      }
  } else {
    #pragma unroll
    for (int mt = 0; mt < 4; ++mt)
      #pragma unroll
      for (int nt = 0; nt < 4; ++nt) {
        size_t base = (size_t)(bm*128 + m0 + mt*16 + fq*4)*MCOLS + bn*128 + n0 + nt*16 + fr;
        Cf[base          ] = acc[mt][nt][0];
        Cf[base + MCOLS  ] = acc[mt][nt][1];
        Cf[base + 2*MCOLS] = acc[mt][nt][2];
        Cf[base + 3*MCOLS] = acc[mt][nt][3];
      }
  }
}

// ---------------- fused aggregation (layers 0,1): bf16 gather, one-pass softmax ----
// out = relu(softmax-agg + b); emits split-bf16 A for next GEMM + el/er for next layer.
__global__ __launch_bounds__(256) void k_agg_f(
    const unsigned short* __restrict__ fsh, const float* __restrict__ el,
    const float* __restrict__ er, const int* __restrict__ row_ptr,
    const int* __restrict__ srcs, const float* __restrict__ bias,
    const float* __restrict__ WalN, const float* __restrict__ WredN,
    unsigned short* __restrict__ Ahi, unsigned short* __restrict__ Alo,
    float* __restrict__ el_next, float* __restrict__ er_next) {
  __shared__ float red_sm[HEADS][8];
  int n = blockIdx.x;
  int h = threadIdx.x >> 6, lane = threadIdx.x & 63;
  int k0 = h*DDIM + lane*4;                 // this thread's 4 output dims
  if (n >= NNODES) {                        // zero the GEMM pad rows
    ushort4 z = {0,0,0,0};
    *(ushort4*)&Ahi[(size_t)n*MCOLS + k0] = z;
    *(ushort4*)&Alo[(size_t)n*MCOLS + k0] = z;
    return;
  }
  int beg = row_ptr[n], end = row_ptr[n+1];
  float er_nh = er[n*HEADS + h];
  float den = 0.f;
  float4 acc = make_float4(0.f, 0.f, 0.f, 0.f);
  const unsigned short* fbase = fsh + h*DDIM + lane*4;
  int i = beg;
  for (; i + 3 < end; i += 4) {
    int s0 = srcs[i], s1 = srcs[i+1], s2 = srcs[i+2], s3 = srcs[i+3];
    float e0 = el[s0*HEADS + h] + er_nh;
    float e1 = el[s1*HEADS + h] + er_nh;
    float e2 = el[s2*HEADS + h] + er_nh;
    float e3 = el[s3*HEADS + h] + er_nh;
    const ushort4 u0 = *(const ushort4*)&fbase[(size_t)s0*MCOLS];
    const ushort4 u1 = *(const ushort4*)&fbase[(size_t)s1*MCOLS];
    const ushort4 u2 = *(const ushort4*)&fbase[(size_t)s2*MCOLS];
    const ushort4 u3 = *(const ushort4*)&fbase[(size_t)s3*MCOLS];
    e0 = e0 >= 0.f ? e0 : 0.2f*e0;  float w0 = expf(e0);
    e1 = e1 >= 0.f ? e1 : 0.2f*e1;  float w1 = expf(e1);
    e2 = e2 >= 0.f ? e2 : 0.2f*e2;  float w2 = expf(e2);
    e3 = e3 >= 0.f ? e3 : 0.2f*e3;  float w3 = expf(e3);
    den += (w0 + w1) + (w2 + w3);
    acc.x = fmaf(w0, bf2f(u0.x), fmaf(w1, bf2f(u1.x), fmaf(w2, bf2f(u2.x), fmaf(w3, bf2f(u3.x), acc.x))));
    acc.y = fmaf(w0, bf2f(u0.y), fmaf(w1, bf2f(u1.y), fmaf(w2, bf2f(u2.y), fmaf(w3, bf2f(u3.y), acc.y))));
    acc.z = fmaf(w0, bf2f(u0.z), fmaf(w1, bf2f(u1.z), fmaf(w2, bf2f(u2.z), fmaf(w3, bf2f(u3.z), acc.z))));
    acc.w = fmaf(w0, bf2f(u0.w), fmaf(w1, bf2f(u1.w), fmaf(w2, bf2f(u2.w), fmaf(w3, bf2f(u3.w), acc.w))));
  }
  for (; i < end; ++i) {
    int s = srcs[i];
    float e = el[s*HEADS + h] + er_nh;
    e = e >= 0.f ? e : 0.2f*e;
    float wgt = expf(e);
    den += wgt;
    const ushort4 u = *(const ushort4*)&fbase[(size_t)s*MCOLS];
    acc.x = fmaf(wgt, bf2f(u.x), acc.x);
    acc.y = fmaf(wgt, bf2f(u.y), acc.y);
    acc.z = fmaf(wgt, bf2f(u.z), acc.z);
    acc.w = fmaf(wgt, bf2f(u.w), acc.w);
  }
  float inv = den > 0.f ? 1.f/den : 0.f;
  const float4 bv = *(const float4*)&bias[k0];
  float4 o;
  o.x = fmaxf(acc.x*inv + bv.x, 0.f);
  o.y = fmaxf(acc.y*inv + bv.y, 0.f);
  o.z = fmaxf(acc.z*inv + bv.z, 0.f);
  o.w = fmaxf(acc.w*inv + bv.w, 0.f);
  // split-bf16 emit (next layer GEMM A)
  ushort4 hv, lv;
  hv.x = f2bf(o.x); lv.x = f2bf(o.x - bf2f(hv.x));
  hv.y = f2bf(o.y); lv.y = f2bf(o.y - bf2f(hv.y));
  hv.z = f2bf(o.z); lv.z = f2bf(o.z - bf2f(hv.z));
  hv.w = f2bf(o.w); lv.w = f2bf(o.w - bf2f(hv.w));
  *(ushort4*)&Ahi[(size_t)n*MCOLS + k0] = hv;
  *(ushort4*)&Alo[(size_t)n*MCOLS + k0] = lv;
  // el_next/er_next[n,h2] = sum_k o[k] * {WalN,WredN}[k,h2]
  const float4 a0 = *(const float4*)&WalN[(k0+0)*HEADS];
  const float4 a1 = *(const float4*)&WalN[(k0+1)*HEADS];
  const float4 a2 = *(const float4*)&WalN[(k0+2)*HEADS];
  const float4 a3 = *(const float4*)&WalN[(k0+3)*HEADS];
  const float4 q0 = *(const float4*)&WredN[(k0+0)*HEADS];
  const float4 q1 = *(const float4*)&WredN[(k0+1)*HEADS];
  const float4 q2 = *(const float4*)&WredN[(k0+2)*HEADS];
  const float4 q3 = *(const float4*)&WredN[(k0+3)*HEADS];
  float p[8];
  p[0] = o.x*a0.x + o.y*a1.x + o.z*a2.x + o.w*a3.x;
  p[1] = o.x*a0.y + o.y*a1.y + o.z*a2.y + o.w*a3.y;
  p[2] = o.x*a0.z + o.y*a1.z + o.z*a2.z + o.w*a3.z;
  p[3] = o.x*a0.w + o.y*a1.w + o.z*a2.w + o.w*a3.w;
  p[4] = o.x*q0.x + o.y*q1.x + o.z*q2.x + o.w*q3.x;
  p[5] = o.x*q0.y + o.y*q1.y + o.z*q2.y + o.w*q3.y;
  p[6] = o.x*q0.z + o.y*q1.z + o.z*q2.z + o.w*q3.z;
  p[7] = o.x*q0.w + o.y*q1.w + o.z*q2.w + o.w*q3.w;
  for (int off = 32; off; off >>= 1)
    #pragma unroll
    for (int j = 0; j < 8; ++j) p[j] += __shfl_xor(p[j], off);
  if (lane == 0)
    #pragma unroll
    for (int j = 0; j < 8; ++j) red_sm[h][j] = p[j];
  __syncthreads();
  if (threadIdx.x < 8) {
    int t = threadIdx.x;
    float v = (red_sm[0][t] + red_sm[1][t]) + (red_sm[2][t] + red_sm[3][t]);
    if (t < 4) el_next[n*HEADS + t] = v;
    else       er_next[n*HEADS + (t-4)] = v;
  }
}

// ---------------- final aggregation (layer 2): fp32 gather, mean over heads ------
__global__ __launch_bounds__(256) void k_agg_out(
    const float* __restrict__ fs, const float* __restrict__ el,
    const float* __restrict__ er, const int* __restrict__ row_ptr,
    const int* __restrict__ srcs, const float* __restrict__ bias,
    float* __restrict__ out) {
  __shared__ float sm[HEADS*DDIM];
  int n = blockIdx.x;
  int h = threadIdx.x >> 6, lane = threadIdx.x & 63;
  int beg = row_ptr[n], end = row_ptr[n+1];
  float er_nh = er[n*HEADS + h];
  float den = 0.f;
  float4 acc = make_float4(0.f, 0.f, 0.f, 0.f);
  const float* fsh = fs + h*DDIM + lane*4;
  int i = beg;
  for (; i + 3 < end; i += 4) {
    int s0 = srcs[i], s1 = srcs[i+1], s2 = srcs[i+2], s3 = srcs[i+3];
    float e0 = el[s0*HEADS + h] + er_nh;
    float e1 = el[s1*HEADS + h] + er_nh;
    float e2 = el[s2*HEADS + h] + er_nh;
    float e3 = el[s3*HEADS + h] + er_nh;
    const float4 v0 = *(const float4*)&fsh[(size_t)s0*MCOLS];
    const float4 v1 = *(const float4*)&fsh[(size_t)s1*MCOLS];
    const float4 v2 = *(const float4*)&fsh[(size_t)s2*MCOLS];
    const float4 v3 = *(const float4*)&fsh[(size_t)s3*MCOLS];
    e0 = e0 >= 0.f ? e0 : 0.2f*e0;  float w0 = expf(e0);
    e1 = e1 >= 0.f ? e1 : 0.2f*e1;  float w1 = expf(e1);
    e2 = e2 >= 0.f ? e2 : 0.2f*e2;  float w2 = expf(e2);
    e3 = e3 >= 0.f ? e3 : 0.2f*e3;  float w3 = expf(e3);
    den += (w0 + w1) + (w2 + w3);
    acc.x = fmaf(w0, v0.x, fmaf(w1, v1.x, fmaf(w2, v2.x, fmaf(w3, v3.x, acc.x))));
    acc.y = fmaf(w0, v0.y, fmaf(w1, v1.y, fmaf(w2, v2.y, fmaf(w3, v3.y, acc.y))));
    acc.z = fmaf(w0, v0.z, fmaf(w1, v1.z, fmaf(w2, v2.z, fmaf(w3, v3.z, acc.z))));
    acc.w = fmaf(w0, v0.w, fmaf(w1, v1.w, fmaf(w2, v2.w, fmaf(w3, v3.w, acc.w))));
  }
  for (; i < end; ++i) {
    int s = srcs[i];
    float e = el[s*HEADS + h] + er_nh;
    e = e >= 0.f ? e : 0.2f*e;
    float wgt = expf(e);
    den += wgt;
    const float4 v = *(const float4*)&fsh[(size_t)s*MCOLS];
    acc.x = fmaf(wgt, v.x, acc.x);
    acc.y = fmaf(wgt, v.y, acc.y);
    acc.z = fmaf(wgt, v.z, acc.z);
    acc.w = fmaf(wgt, v.w, acc.w);
  }
  float inv = den > 0.f ? 1.f/den : 0.f;
  const float4 bv = *(const float4*)&bias[h*DDIM + lane*4];
  acc.x = acc.x*inv + bv.x;
  acc.y = acc.y*inv + bv.y;
  acc.z = acc.z*inv + bv.z;
  acc.w = acc.w*inv + bv.w;
  *(float4*)&sm[h*DDIM + lane*4] = acc;
  __syncthreads();
  int t = threadIdx.x;
  out[(size_t)n*DDIM + t] =
      0.25f*((sm[t] + sm[DDIM + t]) + (sm[2*DDIM + t] + sm[3*DDIM + t]));
}

extern "C" void kernel_launch(void* const* d_in, const int* in_sizes, int n_in,
                              void* d_out, int out_size, void* d_ws, size_t ws_size,
                              hipStream_t stream) {
  const float* x   = (const float*)d_in[0];
  const int*   src = (const int*)d_in[1];
  const int*   dst = (const int*)d_in[2];
  const float* Wsrc[3] = {(const float*)d_in[3], (const float*)d_in[8],  (const float*)d_in[13]};
  const float* Wdst[3] = {(const float*)d_in[4], (const float*)d_in[9],  (const float*)d_in[14]};
  const float* al[3]   = {(const float*)d_in[5], (const float*)d_in[10], (const float*)d_in[15]};
  const float* ar[3]   = {(const float*)d_in[6], (const float*)d_in[11], (const float*)d_in[16]};
  const float* bb[3]   = {(const float*)d_in[7], (const float*)d_in[12], (const float*)d_in[17]};

  char* ws = (char*)d_ws;
  size_t off = 0;
  auto alloc = [&](size_t bytes) { void* p = ws + off; off += (bytes + 255) & ~255ull; return p; };
  float* bufB = (float*)alloc((size_t)NPAD*MCOLS*4);             // fp32 fs (layer 2)
  unsigned short* fshB = (unsigned short*)alloc((size_t)NPAD*MCOLS*2);  // bf16 fs (layers 0,1)
  unsigned short* Ahi = (unsigned short*)alloc((size_t)NPAD*MCOLS*2);
  unsigned short* Alo = (unsigned short*)alloc((size_t)NPAD*MCOLS*2);
  unsigned short* Wth = (unsigned short*)alloc((size_t)MCOLS*MCOLS*2);
  unsigned short* Wtl = (unsigned short*)alloc((size_t)MCOLS*MCOLS*2);
  float* elA  = (float*)alloc((size_t)NNODES*HEADS*4);
  float* elB  = (float*)alloc((size_t)NNODES*HEADS*4);
  float* erA  = (float*)alloc((size_t)NNODES*HEADS*4);
  float* erB  = (float*)alloc((size_t)NNODES*HEADS*4);
  float* WredB[3]; float* WalB[3];
  for (int l = 0; l < 3; ++l) {
    WredB[l] = (float*)alloc(1024*HEADS*4);
    WalB[l]  = (float*)alloc(1024*HEADS*4);
  }
  int* deg     = (int*)alloc((size_t)NNODES*4);
  int* row_ptr = (int*)alloc((size_t)(NNODES+1)*4);
  int* cursor  = (int*)alloc((size_t)NNODES*4);
  int* srcs    = (int*)alloc((size_t)NEDGES*4);
  (void)ws_size; (void)in_sizes; (void)n_in; (void)out_size;

  // CSR build (graph identical across layers)
  k_zero<<<(NNODES+255)/256, 256, 0, stream>>>(deg, NNODES);
  k_hist<<<(NEDGES+255)/256, 256, 0, stream>>>(dst, deg, NEDGES);
  k_scan<<<1, 1024, 0, stream>>>(deg, row_ptr, cursor);
  k_fill<<<(NEDGES+255)/256, 256, 0, stream>>>(src, dst, cursor, srcs, NEDGES);

  const int Fin[3] = {512, 1024, 1024};
  for (int l = 0; l < 3; ++l) {
    k_fold<<<Fin[l], 256, 0, stream>>>(Wdst[l], ar[l], WredB[l], Fin[l]);
    k_fold<<<Fin[l], 256, 0, stream>>>(Wsrc[l], al[l], WalB[l], Fin[l]);
  }

  // layer 0 input prep
  k_cvt_a<<<(NPAD*512/4 + 255)/256, 256, 0, stream>>>(x, Ahi, Alo, NNODES*512, NPAD*512);
  k_eler0<<<NNODES, 256, 0, stream>>>(x, WalB[0], WredB[0], elA, erA);

  float* el_cur = elA; float* el_nxt = elB;
  float* er_cur = erA; float* er_nxt = erB;
  for (int l = 0; l < 3; ++l) {
    int K = Fin[l];
    dim3 gw(MCOLS/32, K/32);
    k_cvt_w<<<gw, 256, 0, stream>>>(Wsrc[l], Wth, Wtl, K);
    dim3 gg(MCOLS/128, NPAD/128);
    k_gemm_mfma<<<gg, 256, 0, stream>>>(Ahi, Alo, Wth, Wtl, bufB, fshB, K, l < 2 ? 1 : 0);
    if (l < 2) {
      k_agg_f<<<NPAD, 256, 0, stream>>>(fshB, el_cur, er_cur, row_ptr, srcs, bb[l],
                                        WalB[l+1], WredB[l+1], Ahi, Alo, el_nxt, er_nxt);
      float* t1 = el_cur; el_cur = el_nxt; el_nxt = t1;
      float* t2 = er_cur; er_cur = er_nxt; er_nxt = t2;
    } else {
      k_agg_out<<<NNODES, 256, 0, stream>>>(bufB, el_cur, er_cur, row_ptr, srcs, bb[l],
                                            (float*)d_out);
    }
  }
}

// Round 5
// 866.880 us; speedup vs baseline: 2.6476x; 1.1439x over previous
//
#include <hip/hip_runtime.h>
#include <hip/hip_bf16.h>
#include <math.h>

#define NNODES 20000
#define NPAD   20096   // 157 * 128
#define NEDGES 320000
#define HEADS  4
#define DDIM   256
#define MCOLS  1024   // H*D

typedef __attribute__((ext_vector_type(8))) short short8;
typedef __attribute__((ext_vector_type(4))) float f32x4;

// bf16 helpers (bit-level, RNE)
__device__ __forceinline__ unsigned short f2bf(float f) {
  unsigned u = __float_as_uint(f);
  unsigned r = (u + 0x7fffu + ((u >> 16) & 1u)) >> 16;
  return (unsigned short)r;
}
__device__ __forceinline__ float bf2f(unsigned short h) {
  return __uint_as_float(((unsigned)h) << 16);
}

__device__ __forceinline__ void async_ld16(void* lds, const void* g) {
  __builtin_amdgcn_global_load_lds(
      (const __attribute__((address_space(1))) unsigned int*)g,
      (__attribute__((address_space(3))) unsigned int*)lds, 16, 0, 0);
}

// ---------------- CSR build (by dst) ----------------
__global__ void k_zero(int* deg, int n) {
  int i = blockIdx.x*blockDim.x + threadIdx.x;
  if (i < n) deg[i] = 0;
}
__global__ void k_hist(const int* __restrict__ dst, int* deg, int e) {
  int i = blockIdx.x*blockDim.x + threadIdx.x;
  if (i < e) atomicAdd(&deg[dst[i]], 1);
}
__global__ void k_scan(const int* __restrict__ deg, int* row_ptr, int* cursor) {
  __shared__ int sm[1024];
  int t = threadIdx.x;
  const int CH = 20;
  int base = t*CH;
  int s = 0;
  #pragma unroll
  for (int i = 0; i < CH; ++i) { int idx = base+i; if (idx < NNODES) s += deg[idx]; }
  int val = s;
  sm[t] = s; __syncthreads();
  for (int off = 1; off < 1024; off <<= 1) {
    int add = (t >= off) ? sm[t-off] : 0;
    __syncthreads();
    val += add; sm[t] = val;
    __syncthreads();
  }
  int run = val - s;
  for (int i = 0; i < CH; ++i) {
    int idx = base+i;
    if (idx < NNODES) { row_ptr[idx] = run; cursor[idx] = run; run += deg[idx]; }
  }
  if (t == 0) row_ptr[NNODES] = NEDGES;
}
__global__ void k_fill(const int* __restrict__ src, const int* __restrict__ dst,
                       int* cursor, int* srcs_sorted, int e) {
  int i = blockIdx.x*blockDim.x + threadIdx.x;
  if (i < e) { int pos = atomicAdd(&cursor[dst[i]], 1); srcs_sorted[pos] = src[i]; }
}

// ---------------- fold: F[k,h] = sum_d W[k, h*D+d] * v[h,d] ----------------
__global__ void k_fold(const float* __restrict__ W, const float* __restrict__ v,
                       float* __restrict__ F, int K) {
  int wave = threadIdx.x >> 6, lane = threadIdx.x & 63;
  int p = blockIdx.x*4 + wave;
  if (p >= K*HEADS) return;
  int k = p >> 2, h = p & 3;
  const float4 wv = *(const float4*)&W[(size_t)k*MCOLS + h*DDIM + lane*4];
  const float4 av = *(const float4*)&v[h*DDIM + lane*4];
  float s = wv.x*av.x + wv.y*av.y + wv.z*av.z + wv.w*av.w;
  for (int off = 32; off; off >>= 1) s += __shfl_xor(s, off);
  if (lane == 0) F[k*HEADS + h] = s;
}

// ---------------- split-bf16 conversion: A (row-major, padded) ----------------
__global__ void k_cvt_a(const float* __restrict__ x, unsigned short* __restrict__ hi,
                        unsigned short* __restrict__ lo, int total, int total_pad) {
  int i = blockIdx.x*blockDim.x + threadIdx.x;
  int idx = i*4;
  if (idx >= total_pad) return;
  float4 v = (idx < total) ? *(const float4*)&x[idx] : make_float4(0.f,0.f,0.f,0.f);
  ushort4 h, l;
  h.x = f2bf(v.x); l.x = f2bf(v.x - bf2f(h.x));
  h.y = f2bf(v.y); l.y = f2bf(v.y - bf2f(h.y));
  h.z = f2bf(v.z); l.z = f2bf(v.z - bf2f(h.z));
  h.w = f2bf(v.w); l.w = f2bf(v.w - bf2f(h.w));
  *(ushort4*)&hi[idx] = h;
  *(ushort4*)&lo[idx] = l;
}

// ---------------- bf16 transpose of W: [K][1024] -> [1024][K] (hi only) ----------
__global__ __launch_bounds__(256) void k_cvt_w(const float* __restrict__ W,
                                               unsigned short* __restrict__ Th, int K) {
  __shared__ float sm[32][33];
  int k0 = blockIdx.y*32, n0 = blockIdx.x*32;
  int t = threadIdx.x;
  int r = t >> 3, c4 = (t & 7)*4;
  *(float4*)&sm[r][c4] = *(const float4*)&W[(size_t)(k0 + r)*MCOLS + n0 + c4];
  __syncthreads();
  ushort4 h;
  h.x = f2bf(sm[c4+0][r]);
  h.y = f2bf(sm[c4+1][r]);
  h.z = f2bf(sm[c4+2][r]);
  h.w = f2bf(sm[c4+3][r]);
  *(ushort4*)&Th[(size_t)(n0 + r)*K + k0 + c4] = h;
}

// ---------------- el0/er0[n,h] = sum_k x[n,k]*{Wal0,Wred0}[k,h] ----------------
__global__ void k_eler0(const float* __restrict__ x, const float* __restrict__ Wal,
                        const float* __restrict__ Wred,
                        float* __restrict__ el, float* __restrict__ er) {
  int n = blockIdx.x;
  int h = threadIdx.x >> 6, lane = threadIdx.x & 63;
  float sl = 0.f, sr = 0.f;
  for (int k = lane; k < 512; k += 64) {
    float xv = x[(size_t)n*512 + k];
    sl = fmaf(xv, Wal[k*HEADS + h], sl);
    sr = fmaf(xv, Wred[k*HEADS + h], sr);
  }
  for (int off = 32; off; off >>= 1) { sl += __shfl_xor(sl, off); sr += __shfl_xor(sr, off); }
  if (lane == 0) { el[n*HEADS + h] = sl; er[n*HEADS + h] = sr; }
}

// ---------------- MFMA GEMM (split-2: Ah*Bh + Al*Bh), bf16 output ----------------
__global__ __launch_bounds__(256) void k_gemm_mfma(
    const unsigned short* __restrict__ Ah, const unsigned short* __restrict__ Al,
    const unsigned short* __restrict__ Bh,
    unsigned short* __restrict__ Fh, int K) {
  __shared__ short sAh[128*32], sAl[128*32], sBh[128*32];
  const int t = threadIdx.x;
  const int w = t >> 6, l = t & 63;
  const int bm = blockIdx.y, bn = blockIdx.x;
  const int m0 = (w >> 1) * 64, n0 = (w & 1) * 64;

  f32x4 acc[4][4];
  #pragma unroll
  for (int i = 0; i < 4; ++i)
    #pragma unroll
    for (int j = 0; j < 4; ++j) acc[i][j] = (f32x4){0.f, 0.f, 0.f, 0.f};

  const int srow = t >> 2, koct = (t & 3) * 8;
  const size_t r64 = (size_t)64 * K;
  const unsigned short* gAh = Ah + (size_t)(bm*128 + srow)*K + koct;
  const unsigned short* gAl = Al + (size_t)(bm*128 + srow)*K + koct;
  const unsigned short* gBh = Bh + (size_t)(bn*128 + srow)*K + koct;
  char* lAh = (char*)sAh + w*1024;
  char* lAl = (char*)sAl + w*1024;
  char* lBh = (char*)sBh + w*1024;

  const int fr = l & 15, fq = l >> 4;

  for (int k0 = 0; k0 < K; k0 += 32) {
    async_ld16(lAh,        gAh + k0);
    async_ld16(lAh + 4096, gAh + k0 + r64);
    async_ld16(lAl,        gAl + k0);
    async_ld16(lAl + 4096, gAl + k0 + r64);
    async_ld16(lBh,        gBh + k0);
    async_ld16(lBh + 4096, gBh + k0 + r64);
    __syncthreads();

    short8 bhv[4];
    #pragma unroll
    for (int nt = 0; nt < 4; ++nt)
      bhv[nt] = *(const short8*)&sBh[(n0 + nt*16 + fr)*32 + fq*8];
    #pragma unroll
    for (int mt = 0; mt < 4; ++mt) {
      int off = (m0 + mt*16 + fr)*32 + fq*8;
      short8 ah = *(const short8*)&sAh[off];
      short8 al = *(const short8*)&sAl[off];
      #pragma unroll
      for (int nt = 0; nt < 4; ++nt) {
        acc[mt][nt] = __builtin_amdgcn_mfma_f32_16x16x32_bf16(ah, bhv[nt], acc[mt][nt], 0, 0, 0);
        acc[mt][nt] = __builtin_amdgcn_mfma_f32_16x16x32_bf16(al, bhv[nt], acc[mt][nt], 0, 0, 0);
      }
    }
    __syncthreads();
  }

  #pragma unroll
  for (int mt = 0; mt < 4; ++mt)
    #pragma unroll
    for (int nt = 0; nt < 4; ++nt) {
      size_t base = (size_t)(bm*128 + m0 + mt*16 + fq*4)*MCOLS + bn*128 + n0 + nt*16 + fr;
      Fh[base          ] = f2bf(acc[mt][nt][0]);
      Fh[base + MCOLS  ] = f2bf(acc[mt][nt][1]);
      Fh[base + 2*MCOLS] = f2bf(acc[mt][nt][2]);
      Fh[base + 3*MCOLS] = f2bf(acc[mt][nt][3]);
    }
}

// ---------------- fused aggregation (layers 0,1): bf16 gather, one-pass softmax ----
__global__ __launch_bounds__(256) void k_agg_f(
    const unsigned short* __restrict__ fsh, const float* __restrict__ el,
    const float* __restrict__ er, const int* __restrict__ row_ptr,
    const int* __restrict__ srcs, const float* __restrict__ bias,
    const float* __restrict__ WalN, const float* __restrict__ WredN,
    unsigned short* __restrict__ Ahi, unsigned short* __restrict__ Alo,
    float* __restrict__ el_next, float* __restrict__ er_next) {
  __shared__ float red_sm[HEADS][8];
  int n = blockIdx.x;
  int h = threadIdx.x >> 6, lane = threadIdx.x & 63;
  int k0 = h*DDIM + lane*4;
  if (n >= NNODES) {
    ushort4 z = {0,0,0,0};
    *(ushort4*)&Ahi[(size_t)n*MCOLS + k0] = z;
    *(ushort4*)&Alo[(size_t)n*MCOLS + k0] = z;
    return;
  }
  int beg = row_ptr[n], end = row_ptr[n+1];
  float er_nh = er[n*HEADS + h];
  float den = 0.f;
  float4 acc = make_float4(0.f, 0.f, 0.f, 0.f);
  const unsigned short* fbase = fsh + h*DDIM + lane*4;
  int i = beg;
  for (; i + 3 < end; i += 4) {
    int s0 = srcs[i], s1 = srcs[i+1], s2 = srcs[i+2], s3 = srcs[i+3];
    float e0 = el[s0*HEADS + h] + er_nh;
    float e1 = el[s1*HEADS + h] + er_nh;
    float e2 = el[s2*HEADS + h] + er_nh;
    float e3 = el[s3*HEADS + h] + er_nh;
    const ushort4 u0 = *(const ushort4*)&fbase[(size_t)s0*MCOLS];
    const ushort4 u1 = *(const ushort4*)&fbase[(size_t)s1*MCOLS];
    const ushort4 u2 = *(const ushort4*)&fbase[(size_t)s2*MCOLS];
    const ushort4 u3 = *(const ushort4*)&fbase[(size_t)s3*MCOLS];
    e0 = e0 >= 0.f ? e0 : 0.2f*e0;  float w0 = expf(e0);
    e1 = e1 >= 0.f ? e1 : 0.2f*e1;  float w1 = expf(e1);
    e2 = e2 >= 0.f ? e2 : 0.2f*e2;  float w2 = expf(e2);
    e3 = e3 >= 0.f ? e3 : 0.2f*e3;  float w3 = expf(e3);
    den += (w0 + w1) + (w2 + w3);
    acc.x = fmaf(w0, bf2f(u0.x), fmaf(w1, bf2f(u1.x), fmaf(w2, bf2f(u2.x), fmaf(w3, bf2f(u3.x), acc.x))));
    acc.y = fmaf(w0, bf2f(u0.y), fmaf(w1, bf2f(u1.y), fmaf(w2, bf2f(u2.y), fmaf(w3, bf2f(u3.y), acc.y))));
    acc.z = fmaf(w0, bf2f(u0.z), fmaf(w1, bf2f(u1.z), fmaf(w2, bf2f(u2.z), fmaf(w3, bf2f(u3.z), acc.z))));
    acc.w = fmaf(w0, bf2f(u0.w), fmaf(w1, bf2f(u1.w), fmaf(w2, bf2f(u2.w), fmaf(w3, bf2f(u3.w), acc.w))));
  }
  for (; i < end; ++i) {
    int s = srcs[i];
    float e = el[s*HEADS + h] + er_nh;
    e = e >= 0.f ? e : 0.2f*e;
    float wgt = expf(e);
    den += wgt;
    const ushort4 u = *(const ushort4*)&fbase[(size_t)s*MCOLS];
    acc.x = fmaf(wgt, bf2f(u.x), acc.x);
    acc.y = fmaf(wgt, bf2f(u.y), acc.y);
    acc.z = fmaf(wgt, bf2f(u.z), acc.z);
    acc.w = fmaf(wgt, bf2f(u.w), acc.w);
  }
  float inv = den > 0.f ? 1.f/den : 0.f;
  const float4 bv = *(const float4*)&bias[k0];
  float4 o;
  o.x = fmaxf(acc.x*inv + bv.x, 0.f);
  o.y = fmaxf(acc.y*inv + bv.y, 0.f);
  o.z = fmaxf(acc.z*inv + bv.z, 0.f);
  o.w = fmaxf(acc.w*inv + bv.w, 0.f);
  ushort4 hv, lv;
  hv.x = f2bf(o.x); lv.x = f2bf(o.x - bf2f(hv.x));
  hv.y = f2bf(o.y); lv.y = f2bf(o.y - bf2f(hv.y));
  hv.z = f2bf(o.z); lv.z = f2bf(o.z - bf2f(hv.z));
  hv.w = f2bf(o.w); lv.w = f2bf(o.w - bf2f(hv.w));
  *(ushort4*)&Ahi[(size_t)n*MCOLS + k0] = hv;
  *(ushort4*)&Alo[(size_t)n*MCOLS + k0] = lv;
  const float4 a0 = *(const float4*)&WalN[(k0+0)*HEADS];
  const float4 a1 = *(const float4*)&WalN[(k0+1)*HEADS];
  const float4 a2 = *(const float4*)&WalN[(k0+2)*HEADS];
  const float4 a3 = *(const float4*)&WalN[(k0+3)*HEADS];
  const float4 q0 = *(const float4*)&WredN[(k0+0)*HEADS];
  const float4 q1 = *(const float4*)&WredN[(k0+1)*HEADS];
  const float4 q2 = *(const float4*)&WredN[(k0+2)*HEADS];
  const float4 q3 = *(const float4*)&WredN[(k0+3)*HEADS];
  float p[8];
  p[0] = o.x*a0.x + o.y*a1.x + o.z*a2.x + o.w*a3.x;
  p[1] = o.x*a0.y + o.y*a1.y + o.z*a2.y + o.w*a3.y;
  p[2] = o.x*a0.z + o.y*a1.z + o.z*a2.z + o.w*a3.z;
  p[3] = o.x*a0.w + o.y*a1.w + o.z*a2.w + o.w*a3.w;
  p[4] = o.x*q0.x + o.y*q1.x + o.z*q2.x + o.w*q3.x;
  p[5] = o.x*q0.y + o.y*q1.y + o.z*q2.y + o.w*q3.y;
  p[6] = o.x*q0.z + o.y*q1.z + o.z*q2.z + o.w*q3.z;
  p[7] = o.x*q0.w + o.y*q1.w + o.z*q2.w + o.w*q3.w;
  for (int off = 32; off; off >>= 1)
    #pragma unroll
    for (int j = 0; j < 8; ++j) p[j] += __shfl_xor(p[j], off);
  if (lane == 0)
    #pragma unroll
    for (int j = 0; j < 8; ++j) red_sm[h][j] = p[j];
  __syncthreads();
  if (threadIdx.x < 8) {
    int t = threadIdx.x;
    float v = (red_sm[0][t] + red_sm[1][t]) + (red_sm[2][t] + red_sm[3][t]);
    if (t < 4) el_next[n*HEADS + t] = v;
    else       er_next[n*HEADS + (t-4)] = v;
  }
}

// ---------------- final aggregation (layer 2): bf16 gather, mean over heads ------
__global__ __launch_bounds__(256) void k_agg_out(
    const unsigned short* __restrict__ fsh, const float* __restrict__ el,
    const float* __restrict__ er, const int* __restrict__ row_ptr,
    const int* __restrict__ srcs, const float* __restrict__ bias,
    float* __restrict__ out) {
  __shared__ float sm[HEADS*DDIM];
  int n = blockIdx.x;
  int h = threadIdx.x >> 6, lane = threadIdx.x & 63;
  int beg = row_ptr[n], end = row_ptr[n+1];
  float er_nh = er[n*HEADS + h];
  float den = 0.f;
  float4 acc = make_float4(0.f, 0.f, 0.f, 0.f);
  const unsigned short* fbase = fsh + h*DDIM + lane*4;
  int i = beg;
  for (; i + 3 < end; i += 4) {
    int s0 = srcs[i], s1 = srcs[i+1], s2 = srcs[i+2], s3 = srcs[i+3];
    float e0 = el[s0*HEADS + h] + er_nh;
    float e1 = el[s1*HEADS + h] + er_nh;
    float e2 = el[s2*HEADS + h] + er_nh;
    float e3 = el[s3*HEADS + h] + er_nh;
    const ushort4 u0 = *(const ushort4*)&fbase[(size_t)s0*MCOLS];
    const ushort4 u1 = *(const ushort4*)&fbase[(size_t)s1*MCOLS];
    const ushort4 u2 = *(const ushort4*)&fbase[(size_t)s2*MCOLS];
    const ushort4 u3 = *(const ushort4*)&fbase[(size_t)s3*MCOLS];
    e0 = e0 >= 0.f ? e0 : 0.2f*e0;  float w0 = expf(e0);
    e1 = e1 >= 0.f ? e1 : 0.2f*e1;  float w1 = expf(e1);
    e2 = e2 >= 0.f ? e2 : 0.2f*e2;  float w2 = expf(e2);
    e3 = e3 >= 0.f ? e3 : 0.2f*e3;  float w3 = expf(e3);
    den += (w0 + w1) + (w2 + w3);
    acc.x = fmaf(w0, bf2f(u0.x), fmaf(w1, bf2f(u1.x), fmaf(w2, bf2f(u2.x), fmaf(w3, bf2f(u3.x), acc.x))));
    acc.y = fmaf(w0, bf2f(u0.y), fmaf(w1, bf2f(u1.y), fmaf(w2, bf2f(u2.y), fmaf(w3, bf2f(u3.y), acc.y))));
    acc.z = fmaf(w0, bf2f(u0.z), fmaf(w1, bf2f(u1.z), fmaf(w2, bf2f(u2.z), fmaf(w3, bf2f(u3.z), acc.z))));
    acc.w = fmaf(w0, bf2f(u0.w), fmaf(w1, bf2f(u1.w), fmaf(w2, bf2f(u2.w), fmaf(w3, bf2f(u3.w), acc.w))));
  }
  for (; i < end; ++i) {
    int s = srcs[i];
    float e = el[s*HEADS + h] + er_nh;
    e = e >= 0.f ? e : 0.2f*e;
    float wgt = expf(e);
    den += wgt;
    const ushort4 u = *(const ushort4*)&fbase[(size_t)s*MCOLS];
    acc.x = fmaf(wgt, bf2f(u.x), acc.x);
    acc.y = fmaf(wgt, bf2f(u.y), acc.y);
    acc.z = fmaf(wgt, bf2f(u.z), acc.z);
    acc.w = fmaf(wgt, bf2f(u.w), acc.w);
  }
  float inv = den > 0.f ? 1.f/den : 0.f;
  const float4 bv = *(const float4*)&bias[h*DDIM + lane*4];
  acc.x = acc.x*inv + bv.x;
  acc.y = acc.y*inv + bv.y;
  acc.z = acc.z*inv + bv.z;
  acc.w = acc.w*inv + bv.w;
  *(float4*)&sm[h*DDIM + lane*4] = acc;
  __syncthreads();
  int t = threadIdx.x;
  out[(size_t)n*DDIM + t] =
      0.25f*((sm[t] + sm[DDIM + t]) + (sm[2*DDIM + t] + sm[3*DDIM + t]));
}

extern "C" void kernel_launch(void* const* d_in, const int* in_sizes, int n_in,
                              void* d_out, int out_size, void* d_ws, size_t ws_size,
                              hipStream_t stream) {
  const float* x   = (const float*)d_in[0];
  const int*   src = (const int*)d_in[1];
  const int*   dst = (const int*)d_in[2];
  const float* Wsrc[3] = {(const float*)d_in[3], (const float*)d_in[8],  (const float*)d_in[13]};
  const float* Wdst[3] = {(const float*)d_in[4], (const float*)d_in[9],  (const float*)d_in[14]};
  const float* al[3]   = {(const float*)d_in[5], (const float*)d_in[10], (const float*)d_in[15]};
  const float* ar[3]   = {(const float*)d_in[6], (const float*)d_in[11], (const float*)d_in[16]};
  const float* bb[3]   = {(const float*)d_in[7], (const float*)d_in[12], (const float*)d_in[17]};

  char* ws = (char*)d_ws;
  size_t off = 0;
  auto alloc = [&](size_t bytes) { void* p = ws + off; off += (bytes + 255) & ~255ull; return p; };
  unsigned short* fshB = (unsigned short*)alloc((size_t)NPAD*MCOLS*2);  // bf16 fs
  unsigned short* Ahi = (unsigned short*)alloc((size_t)NPAD*MCOLS*2);
  unsigned short* Alo = (unsigned short*)alloc((size_t)NPAD*MCOLS*2);
  unsigned short* Wth = (unsigned short*)alloc((size_t)MCOLS*MCOLS*2);
  float* elA  = (float*)alloc((size_t)NNODES*HEADS*4);
  float* elB  = (float*)alloc((size_t)NNODES*HEADS*4);
  float* erA  = (float*)alloc((size_t)NNODES*HEADS*4);
  float* erB  = (float*)alloc((size_t)NNODES*HEADS*4);
  float* WredB[3]; float* WalB[3];
  for (int l = 0; l < 3; ++l) {
    WredB[l] = (float*)alloc(1024*HEADS*4);
    WalB[l]  = (float*)alloc(1024*HEADS*4);
  }
  int* deg     = (int*)alloc((size_t)NNODES*4);
  int* row_ptr = (int*)alloc((size_t)(NNODES+1)*4);
  int* cursor  = (int*)alloc((size_t)NNODES*4);
  int* srcs    = (int*)alloc((size_t)NEDGES*4);
  (void)ws_size; (void)in_sizes; (void)n_in; (void)out_size;

  // CSR build (graph identical across layers)
  k_zero<<<(NNODES+255)/256, 256, 0, stream>>>(deg, NNODES);
  k_hist<<<(NEDGES+255)/256, 256, 0, stream>>>(dst, deg, NEDGES);
  k_scan<<<1, 1024, 0, stream>>>(deg, row_ptr, cursor);
  k_fill<<<(NEDGES+255)/256, 256, 0, stream>>>(src, dst, cursor, srcs, NEDGES);

  const int Fin[3] = {512, 1024, 1024};
  for (int l = 0; l < 3; ++l) {
    k_fold<<<Fin[l], 256, 0, stream>>>(Wdst[l], ar[l], WredB[l], Fin[l]);
    k_fold<<<Fin[l], 256, 0, stream>>>(Wsrc[l], al[l], WalB[l], Fin[l]);
  }

  // layer 0 input prep
  k_cvt_a<<<(NPAD*512/4 + 255)/256, 256, 0, stream>>>(x, Ahi, Alo, NNODES*512, NPAD*512);
  k_eler0<<<NNODES, 256, 0, stream>>>(x, WalB[0], WredB[0], elA, erA);

  float* el_cur = elA; float* el_nxt = elB;
  float* er_cur = erA; float* er_nxt = erB;
  for (int l = 0; l < 3; ++l) {
    int K = Fin[l];
    dim3 gw(MCOLS/32, K/32);
    k_cvt_w<<<gw, 256, 0, stream>>>(Wsrc[l], Wth, K);
    dim3 gg(MCOLS/128, NPAD/128);
    k_gemm_mfma<<<gg, 256, 0, stream>>>(Ahi, Alo, Wth, fshB, K);
    if (l < 2) {
      k_agg_f<<<NPAD, 256, 0, stream>>>(fshB, el_cur, er_cur, row_ptr, srcs, bb[l],
                                        WalB[l+1], WredB[l+1], Ahi, Alo, el_nxt, er_nxt);
      float* t1 = el_cur; el_cur = el_nxt; el_nxt = t1;
      float* t2 = er_cur; er_cur = er_nxt; er_nxt = t2;
    } else {
      k_agg_out<<<NNODES, 256, 0, stream>>>(fshB, el_cur, er_cur, row_ptr, srcs, bb[l],
                                            (float*)d_out);
    }
  }
}

// Round 6
// 807.507 us; speedup vs baseline: 2.8423x; 1.0735x over previous
//
#include <hip/hip_runtime.h>
#include <hip/hip_bf16.h>
#include <math.h>

#define NNODES 20000
#define NPAD   20480   // 160 * 128 (160 bm strips -> 20 per XCD)
#define NBM    160
#define NEDGES 320000
#define HEADS  4
#define DDIM   256
#define MCOLS  1024   // H*D

typedef __attribute__((ext_vector_type(8))) short short8;
typedef __attribute__((ext_vector_type(4))) float f32x4;

// bf16 helpers (bit-level, RNE)
__device__ __forceinline__ unsigned short f2bf(float f) {
  unsigned u = __float_as_uint(f);
  unsigned r = (u + 0x7fffu + ((u >> 16) & 1u)) >> 16;
  return (unsigned short)r;
}
__device__ __forceinline__ float bf2f(unsigned short h) {
  return __uint_as_float(((unsigned)h) << 16);
}

__device__ __forceinline__ void async_ld16(void* lds, const void* g) {
  __builtin_amdgcn_global_load_lds(
      (const __attribute__((address_space(1))) unsigned int*)g,
      (__attribute__((address_space(3))) unsigned int*)lds, 16, 0, 0);
}

// ---------------- CSR build (by dst) ----------------
__global__ void k_zero(int* deg, int n) {
  int i = blockIdx.x*blockDim.x + threadIdx.x;
  if (i < n) deg[i] = 0;
}
__global__ void k_hist(const int* __restrict__ dst, int* deg, int e) {
  int i = blockIdx.x*blockDim.x + threadIdx.x;
  if (i < e) atomicAdd(&deg[dst[i]], 1);
}
__global__ void k_scan(const int* __restrict__ deg, int* row_ptr, int* cursor) {
  __shared__ int sm[1024];
  int t = threadIdx.x;
  const int CH = 20;
  int base = t*CH;
  int s = 0;
  #pragma unroll
  for (int i = 0; i < CH; ++i) { int idx = base+i; if (idx < NNODES) s += deg[idx]; }
  int val = s;
  sm[t] = s; __syncthreads();
  for (int off = 1; off < 1024; off <<= 1) {
    int add = (t >= off) ? sm[t-off] : 0;
    __syncthreads();
    val += add; sm[t] = val;
    __syncthreads();
  }
  int run = val - s;
  for (int i = 0; i < CH; ++i) {
    int idx = base+i;
    if (idx < NNODES) { row_ptr[idx] = run; cursor[idx] = run; run += deg[idx]; }
  }
  if (t == 0) row_ptr[NNODES] = NEDGES;
}
__global__ void k_fill(const int* __restrict__ src, const int* __restrict__ dst,
                       int* cursor, int* srcs_sorted, int e) {
  int i = blockIdx.x*blockDim.x + threadIdx.x;
  if (i < e) { int pos = atomicAdd(&cursor[dst[i]], 1); srcs_sorted[pos] = src[i]; }
}

// ---------------- fold: F[k,h] = sum_d W[k, h*D+d] * v[h,d] ----------------
__global__ void k_fold(const float* __restrict__ W, const float* __restrict__ v,
                       float* __restrict__ F, int K) {
  int wave = threadIdx.x >> 6, lane = threadIdx.x & 63;
  int p = blockIdx.x*4 + wave;
  if (p >= K*HEADS) return;
  int k = p >> 2, h = p & 3;
  const float4 wv = *(const float4*)&W[(size_t)k*MCOLS + h*DDIM + lane*4];
  const float4 av = *(const float4*)&v[h*DDIM + lane*4];
  float s = wv.x*av.x + wv.y*av.y + wv.z*av.z + wv.w*av.w;
  for (int off = 32; off; off >>= 1) s += __shfl_xor(s, off);
  if (lane == 0) F[k*HEADS + h] = s;
}

// ---------------- split-bf16 conversion: A (row-major, padded) ----------------
__global__ void k_cvt_a(const float* __restrict__ x, unsigned short* __restrict__ hi,
                        unsigned short* __restrict__ lo, int total, int total_pad) {
  int i = blockIdx.x*blockDim.x + threadIdx.x;
  int idx = i*4;
  if (idx >= total_pad) return;
  float4 v = (idx < total) ? *(const float4*)&x[idx] : make_float4(0.f,0.f,0.f,0.f);
  ushort4 h, l;
  h.x = f2bf(v.x); l.x = f2bf(v.x - bf2f(h.x));
  h.y = f2bf(v.y); l.y = f2bf(v.y - bf2f(h.y));
  h.z = f2bf(v.z); l.z = f2bf(v.z - bf2f(h.z));
  h.w = f2bf(v.w); l.w = f2bf(v.w - bf2f(h.w));
  *(ushort4*)&hi[idx] = h;
  *(ushort4*)&lo[idx] = l;
}

// ---------------- bf16 transpose of W: [K][1024] -> [1024][K] (hi only) ----------
__global__ __launch_bounds__(256) void k_cvt_w(const float* __restrict__ W,
                                               unsigned short* __restrict__ Th, int K) {
  __shared__ float sm[32][33];
  int k0 = blockIdx.y*32, n0 = blockIdx.x*32;
  int t = threadIdx.x;
  int r = t >> 3, c4 = (t & 7)*4;
  *(float4*)&sm[r][c4] = *(const float4*)&W[(size_t)(k0 + r)*MCOLS + n0 + c4];
  __syncthreads();
  ushort4 h;
  h.x = f2bf(sm[c4+0][r]);
  h.y = f2bf(sm[c4+1][r]);
  h.z = f2bf(sm[c4+2][r]);
  h.w = f2bf(sm[c4+3][r]);
  *(ushort4*)&Th[(size_t)(n0 + r)*K + k0 + c4] = h;
}

// ---------------- el0/er0[n,h] = sum_k x[n,k]*{Wal0,Wred0}[k,h] ----------------
__global__ void k_eler0(const float* __restrict__ x, const float* __restrict__ Wal,
                        const float* __restrict__ Wred,
                        float* __restrict__ el, float* __restrict__ er) {
  int n = blockIdx.x;
  int h = threadIdx.x >> 6, lane = threadIdx.x & 63;
  float sl = 0.f, sr = 0.f;
  for (int k = lane; k < 512; k += 64) {
    float xv = x[(size_t)n*512 + k];
    sl = fmaf(xv, Wal[k*HEADS + h], sl);
    sr = fmaf(xv, Wred[k*HEADS + h], sr);
  }
  for (int off = 32; off; off >>= 1) { sl += __shfl_xor(sl, off); sr += __shfl_xor(sr, off); }
  if (lane == 0) { el[n*HEADS + h] = sl; er[n*HEADS + h] = sr; }
}

// ---------------- MFMA GEMM (split-2: Ah*Bh + Al*Bh), bf16 output ----------------
// 1D grid of NBM*8 blocks, XCD-aware swizzle: blocks with b%8==x land on XCD x
// (round-robin dispatch assumption); each XCD owns 20 exclusive bm strips,
// traversed bm-major so all 8 bn of a strip are concurrently resident -> A strip
// fetched ~once per device, B stays L2-resident.
__global__ __launch_bounds__(256, 3) void k_gemm_mfma(
    const unsigned short* __restrict__ Ah, const unsigned short* __restrict__ Al,
    const unsigned short* __restrict__ Bh,
    unsigned short* __restrict__ Fh, int K) {
  __shared__ short sAh[128*32], sAl[128*32], sBh[128*32];
  const int t = threadIdx.x;
  const int w = t >> 6, l = t & 63;
  const int b = blockIdx.x;
  const int xcd = b & 7, kk = b >> 3;
  const int bm = xcd*20 + (kk >> 3), bn = kk & 7;
  const int m0 = (w >> 1) * 64, n0 = (w & 1) * 64;

  f32x4 acc[4][4];
  #pragma unroll
  for (int i = 0; i < 4; ++i)
    #pragma unroll
    for (int j = 0; j < 4; ++j) acc[i][j] = (f32x4){0.f, 0.f, 0.f, 0.f};

  const int srow = t >> 2, koct = (t & 3) * 8;
  const size_t r64 = (size_t)64 * K;
  const unsigned short* gAh = Ah + (size_t)(bm*128 + srow)*K + koct;
  const unsigned short* gAl = Al + (size_t)(bm*128 + srow)*K + koct;
  const unsigned short* gBh = Bh + (size_t)(bn*128 + srow)*K + koct;
  char* lAh = (char*)sAh + w*1024;
  char* lAl = (char*)sAl + w*1024;
  char* lBh = (char*)sBh + w*1024;

  const int fr = l & 15, fq = l >> 4;

  for (int k0 = 0; k0 < K; k0 += 32) {
    async_ld16(lAh,        gAh + k0);
    async_ld16(lAh + 4096, gAh + k0 + r64);
    async_ld16(lAl,        gAl + k0);
    async_ld16(lAl + 4096, gAl + k0 + r64);
    async_ld16(lBh,        gBh + k0);
    async_ld16(lBh + 4096, gBh + k0 + r64);
    __syncthreads();

    short8 bhv[4];
    #pragma unroll
    for (int nt = 0; nt < 4; ++nt)
      bhv[nt] = *(const short8*)&sBh[(n0 + nt*16 + fr)*32 + fq*8];
    #pragma unroll
    for (int mt = 0; mt < 4; ++mt) {
      int off = (m0 + mt*16 + fr)*32 + fq*8;
      short8 ah = *(const short8*)&sAh[off];
      short8 al = *(const short8*)&sAl[off];
      #pragma unroll
      for (int nt = 0; nt < 4; ++nt) {
        acc[mt][nt] = __builtin_amdgcn_mfma_f32_16x16x32_bf16(ah, bhv[nt], acc[mt][nt], 0, 0, 0);
        acc[mt][nt] = __builtin_amdgcn_mfma_f32_16x16x32_bf16(al, bhv[nt], acc[mt][nt], 0, 0, 0);
      }
    }
    __syncthreads();
  }

  #pragma unroll
  for (int mt = 0; mt < 4; ++mt)
    #pragma unroll
    for (int nt = 0; nt < 4; ++nt) {
      size_t base = (size_t)(bm*128 + m0 + mt*16 + fq*4)*MCOLS + bn*128 + n0 + nt*16 + fr;
      Fh[base          ] = f2bf(acc[mt][nt][0]);
      Fh[base + MCOLS  ] = f2bf(acc[mt][nt][1]);
      Fh[base + 2*MCOLS] = f2bf(acc[mt][nt][2]);
      Fh[base + 3*MCOLS] = f2bf(acc[mt][nt][3]);
    }
}

// ---------------- fused aggregation (layers 0,1): bf16 gather, one-pass softmax ----
__global__ __launch_bounds__(256) void k_agg_f(
    const unsigned short* __restrict__ fsh, const float* __restrict__ el,
    const float* __restrict__ er, const int* __restrict__ row_ptr,
    const int* __restrict__ srcs, const float* __restrict__ bias,
    const float* __restrict__ WalN, const float* __restrict__ WredN,
    unsigned short* __restrict__ Ahi, unsigned short* __restrict__ Alo,
    float* __restrict__ el_next, float* __restrict__ er_next) {
  __shared__ float red_sm[HEADS][8];
  int n = blockIdx.x;
  int h = threadIdx.x >> 6, lane = threadIdx.x & 63;
  int k0 = h*DDIM + lane*4;
  if (n >= NNODES) {
    ushort4 z = {0,0,0,0};
    *(ushort4*)&Ahi[(size_t)n*MCOLS + k0] = z;
    *(ushort4*)&Alo[(size_t)n*MCOLS + k0] = z;
    return;
  }
  int beg = row_ptr[n], end = row_ptr[n+1];
  float er_nh = er[n*HEADS + h];
  float den = 0.f;
  float4 acc = make_float4(0.f, 0.f, 0.f, 0.f);
  const unsigned short* fbase = fsh + h*DDIM + lane*4;
  int i = beg;
  for (; i + 3 < end; i += 4) {
    int s0 = srcs[i], s1 = srcs[i+1], s2 = srcs[i+2], s3 = srcs[i+3];
    float e0 = el[s0*HEADS + h] + er_nh;
    float e1 = el[s1*HEADS + h] + er_nh;
    float e2 = el[s2*HEADS + h] + er_nh;
    float e3 = el[s3*HEADS + h] + er_nh;
    const ushort4 u0 = *(const ushort4*)&fbase[(size_t)s0*MCOLS];
    const ushort4 u1 = *(const ushort4*)&fbase[(size_t)s1*MCOLS];
    const ushort4 u2 = *(const ushort4*)&fbase[(size_t)s2*MCOLS];
    const ushort4 u3 = *(const ushort4*)&fbase[(size_t)s3*MCOLS];
    e0 = e0 >= 0.f ? e0 : 0.2f*e0;  float w0 = expf(e0);
    e1 = e1 >= 0.f ? e1 : 0.2f*e1;  float w1 = expf(e1);
    e2 = e2 >= 0.f ? e2 : 0.2f*e2;  float w2 = expf(e2);
    e3 = e3 >= 0.f ? e3 : 0.2f*e3;  float w3 = expf(e3);
    den += (w0 + w1) + (w2 + w3);
    acc.x = fmaf(w0, bf2f(u0.x), fmaf(w1, bf2f(u1.x), fmaf(w2, bf2f(u2.x), fmaf(w3, bf2f(u3.x), acc.x))));
    acc.y = fmaf(w0, bf2f(u0.y), fmaf(w1, bf2f(u1.y), fmaf(w2, bf2f(u2.y), fmaf(w3, bf2f(u3.y), acc.y))));
    acc.z = fmaf(w0, bf2f(u0.z), fmaf(w1, bf2f(u1.z), fmaf(w2, bf2f(u2.z), fmaf(w3, bf2f(u3.z), acc.z))));
    acc.w = fmaf(w0, bf2f(u0.w), fmaf(w1, bf2f(u1.w), fmaf(w2, bf2f(u2.w), fmaf(w3, bf2f(u3.w), acc.w))));
  }
  for (; i < end; ++i) {
    int s = srcs[i];
    float e = el[s*HEADS + h] + er_nh;
    e = e >= 0.f ? e : 0.2f*e;
    float wgt = expf(e);
    den += wgt;
    const ushort4 u = *(const ushort4*)&fbase[(size_t)s*MCOLS];
    acc.x = fmaf(wgt, bf2f(u.x), acc.x);
    acc.y = fmaf(wgt, bf2f(u.y), acc.y);
    acc.z = fmaf(wgt, bf2f(u.z), acc.z);
    acc.w = fmaf(wgt, bf2f(u.w), acc.w);
  }
  float inv = den > 0.f ? 1.f/den : 0.f;
  const float4 bv = *(const float4*)&bias[k0];
  float4 o;
  o.x = fmaxf(acc.x*inv + bv.x, 0.f);
  o.y = fmaxf(acc.y*inv + bv.y, 0.f);
  o.z = fmaxf(acc.z*inv + bv.z, 0.f);
  o.w = fmaxf(acc.w*inv + bv.w, 0.f);
  ushort4 hv, lv;
  hv.x = f2bf(o.x); lv.x = f2bf(o.x - bf2f(hv.x));
  hv.y = f2bf(o.y); lv.y = f2bf(o.y - bf2f(hv.y));
  hv.z = f2bf(o.z); lv.z = f2bf(o.z - bf2f(hv.z));
  hv.w = f2bf(o.w); lv.w = f2bf(o.w - bf2f(hv.w));
  *(ushort4*)&Ahi[(size_t)n*MCOLS + k0] = hv;
  *(ushort4*)&Alo[(size_t)n*MCOLS + k0] = lv;
  const float4 a0 = *(const float4*)&WalN[(k0+0)*HEADS];
  const float4 a1 = *(const float4*)&WalN[(k0+1)*HEADS];
  const float4 a2 = *(const float4*)&WalN[(k0+2)*HEADS];
  const float4 a3 = *(const float4*)&WalN[(k0+3)*HEADS];
  const float4 q0 = *(const float4*)&WredN[(k0+0)*HEADS];
  const float4 q1 = *(const float4*)&WredN[(k0+1)*HEADS];
  const float4 q2 = *(const float4*)&WredN[(k0+2)*HEADS];
  const float4 q3 = *(const float4*)&WredN[(k0+3)*HEADS];
  float p[8];
  p[0] = o.x*a0.x + o.y*a1.x + o.z*a2.x + o.w*a3.x;
  p[1] = o.x*a0.y + o.y*a1.y + o.z*a2.y + o.w*a3.y;
  p[2] = o.x*a0.z + o.y*a1.z + o.z*a2.z + o.w*a3.z;
  p[3] = o.x*a0.w + o.y*a1.w + o.z*a2.w + o.w*a3.w;
  p[4] = o.x*q0.x + o.y*q1.x + o.z*q2.x + o.w*q3.x;
  p[5] = o.x*q0.y + o.y*q1.y + o.z*q2.y + o.w*q3.y;
  p[6] = o.x*q0.z + o.y*q1.z + o.z*q2.z + o.w*q3.z;
  p[7] = o.x*q0.w + o.y*q1.w + o.z*q2.w + o.w*q3.w;
  for (int off = 32; off; off >>= 1)
    #pragma unroll
    for (int j = 0; j < 8; ++j) p[j] += __shfl_xor(p[j], off);
  if (lane == 0)
    #pragma unroll
    for (int j = 0; j < 8; ++j) red_sm[h][j] = p[j];
  __syncthreads();
  if (threadIdx.x < 8) {
    int t = threadIdx.x;
    float v = (red_sm[0][t] + red_sm[1][t]) + (red_sm[2][t] + red_sm[3][t]);
    if (t < 4) el_next[n*HEADS + t] = v;
    else       er_next[n*HEADS + (t-4)] = v;
  }
}

// ---------------- final aggregation (layer 2): bf16 gather, mean over heads ------
__global__ __launch_bounds__(256) void k_agg_out(
    const unsigned short* __restrict__ fsh, const float* __restrict__ el,
    const float* __restrict__ er, const int* __restrict__ row_ptr,
    const int* __restrict__ srcs, const float* __restrict__ bias,
    float* __restrict__ out) {
  __shared__ float sm[HEADS*DDIM];
  int n = blockIdx.x;
  int h = threadIdx.x >> 6, lane = threadIdx.x & 63;
  int beg = row_ptr[n], end = row_ptr[n+1];
  float er_nh = er[n*HEADS + h];
  float den = 0.f;
  float4 acc = make_float4(0.f, 0.f, 0.f, 0.f);
  const unsigned short* fbase = fsh + h*DDIM + lane*4;
  int i = beg;
  for (; i + 3 < end; i += 4) {
    int s0 = srcs[i], s1 = srcs[i+1], s2 = srcs[i+2], s3 = srcs[i+3];
    float e0 = el[s0*HEADS + h] + er_nh;
    float e1 = el[s1*HEADS + h] + er_nh;
    float e2 = el[s2*HEADS + h] + er_nh;
    float e3 = el[s3*HEADS + h] + er_nh;
    const ushort4 u0 = *(const ushort4*)&fbase[(size_t)s0*MCOLS];
    const ushort4 u1 = *(const ushort4*)&fbase[(size_t)s1*MCOLS];
    const ushort4 u2 = *(const ushort4*)&fbase[(size_t)s2*MCOLS];
    const ushort4 u3 = *(const ushort4*)&fbase[(size_t)s3*MCOLS];
    e0 = e0 >= 0.f ? e0 : 0.2f*e0;  float w0 = expf(e0);
    e1 = e1 >= 0.f ? e1 : 0.2f*e1;  float w1 = expf(e1);
    e2 = e2 >= 0.f ? e2 : 0.2f*e2;  float w2 = expf(e2);
    e3 = e3 >= 0.f ? e3 : 0.2f*e3;  float w3 = expf(e3);
    den += (w0 + w1) + (w2 + w3);
    acc.x = fmaf(w0, bf2f(u0.x), fmaf(w1, bf2f(u1.x), fmaf(w2, bf2f(u2.x), fmaf(w3, bf2f(u3.x), acc.x))));
    acc.y = fmaf(w0, bf2f(u0.y), fmaf(w1, bf2f(u1.y), fmaf(w2, bf2f(u2.y), fmaf(w3, bf2f(u3.y), acc.y))));
    acc.z = fmaf(w0, bf2f(u0.z), fmaf(w1, bf2f(u1.z), fmaf(w2, bf2f(u2.z), fmaf(w3, bf2f(u3.z), acc.z))));
    acc.w = fmaf(w0, bf2f(u0.w), fmaf(w1, bf2f(u1.w), fmaf(w2, bf2f(u2.w), fmaf(w3, bf2f(u3.w), acc.w))));
  }
  for (; i < end; ++i) {
    int s = srcs[i];
    float e = el[s*HEADS + h] + er_nh;
    e = e >= 0.f ? e : 0.2f*e;
    float wgt = expf(e);
    den += wgt;
    const ushort4 u = *(const ushort4*)&fbase[(size_t)s*MCOLS];
    acc.x = fmaf(wgt, bf2f(u.x), acc.x);
    acc.y = fmaf(wgt, bf2f(u.y), acc.y);
    acc.z = fmaf(wgt, bf2f(u.z), acc.z);
    acc.w = fmaf(wgt, bf2f(u.w), acc.w);
  }
  float inv = den > 0.f ? 1.f/den : 0.f;
  const float4 bv = *(const float4*)&bias[h*DDIM + lane*4];
  acc.x = acc.x*inv + bv.x;
  acc.y = acc.y*inv + bv.y;
  acc.z = acc.z*inv + bv.z;
  acc.w = acc.w*inv + bv.w;
  *(float4*)&sm[h*DDIM + lane*4] = acc;
  __syncthreads();
  int t = threadIdx.x;
  out[(size_t)n*DDIM + t] =
      0.25f*((sm[t] + sm[DDIM + t]) + (sm[2*DDIM + t] + sm[3*DDIM + t]));
}

extern "C" void kernel_launch(void* const* d_in, const int* in_sizes, int n_in,
                              void* d_out, int out_size, void* d_ws, size_t ws_size,
                              hipStream_t stream) {
  const float* x   = (const float*)d_in[0];
  const int*   src = (const int*)d_in[1];
  const int*   dst = (const int*)d_in[2];
  const float* Wsrc[3] = {(const float*)d_in[3], (const float*)d_in[8],  (const float*)d_in[13]};
  const float* Wdst[3] = {(const float*)d_in[4], (const float*)d_in[9],  (const float*)d_in[14]};
  const float* al[3]   = {(const float*)d_in[5], (const float*)d_in[10], (const float*)d_in[15]};
  const float* ar[3]   = {(const float*)d_in[6], (const float*)d_in[11], (const float*)d_in[16]};
  const float* bb[3]   = {(const float*)d_in[7], (const float*)d_in[12], (const float*)d_in[17]};

  char* ws = (char*)d_ws;
  size_t off = 0;
  auto alloc = [&](size_t bytes) { void* p = ws + off; off += (bytes + 255) & ~255ull; return p; };
  unsigned short* fshB = (unsigned short*)alloc((size_t)NPAD*MCOLS*2);  // bf16 fs
  unsigned short* Ahi = (unsigned short*)alloc((size_t)NPAD*MCOLS*2);
  unsigned short* Alo = (unsigned short*)alloc((size_t)NPAD*MCOLS*2);
  unsigned short* Wth = (unsigned short*)alloc((size_t)MCOLS*MCOLS*2);
  float* elA  = (float*)alloc((size_t)NNODES*HEADS*4);
  float* elB  = (float*)alloc((size_t)NNODES*HEADS*4);
  float* erA  = (float*)alloc((size_t)NNODES*HEADS*4);
  float* erB  = (float*)alloc((size_t)NNODES*HEADS*4);
  float* WredB[3]; float* WalB[3];
  for (int l = 0; l < 3; ++l) {
    WredB[l] = (float*)alloc(1024*HEADS*4);
    WalB[l]  = (float*)alloc(1024*HEADS*4);
  }
  int* deg     = (int*)alloc((size_t)NNODES*4);
  int* row_ptr = (int*)alloc((size_t)(NNODES+1)*4);
  int* cursor  = (int*)alloc((size_t)NNODES*4);
  int* srcs    = (int*)alloc((size_t)NEDGES*4);
  (void)ws_size; (void)in_sizes; (void)n_in; (void)out_size;

  // CSR build (graph identical across layers)
  k_zero<<<(NNODES+255)/256, 256, 0, stream>>>(deg, NNODES);
  k_hist<<<(NEDGES+255)/256, 256, 0, stream>>>(dst, deg, NEDGES);
  k_scan<<<1, 1024, 0, stream>>>(deg, row_ptr, cursor);
  k_fill<<<(NEDGES+255)/256, 256, 0, stream>>>(src, dst, cursor, srcs, NEDGES);

  const int Fin[3] = {512, 1024, 1024};
  for (int l = 0; l < 3; ++l) {
    k_fold<<<Fin[l], 256, 0, stream>>>(Wdst[l], ar[l], WredB[l], Fin[l]);
    k_fold<<<Fin[l], 256, 0, stream>>>(Wsrc[l], al[l], WalB[l], Fin[l]);
  }

  // layer 0 input prep
  k_cvt_a<<<(NPAD*512/4 + 255)/256, 256, 0, stream>>>(x, Ahi, Alo, NNODES*512, NPAD*512);
  k_eler0<<<NNODES, 256, 0, stream>>>(x, WalB[0], WredB[0], elA, erA);

  float* el_cur = elA; float* el_nxt = elB;
  float* er_cur = erA; float* er_nxt = erB;
  for (int l = 0; l < 3; ++l) {
    int K = Fin[l];
    dim3 gw(MCOLS/32, K/32);
    k_cvt_w<<<gw, 256, 0, stream>>>(Wsrc[l], Wth, K);
    k_gemm_mfma<<<NBM*8, 256, 0, stream>>>(Ahi, Alo, Wth, fshB, K);
    if (l < 2) {
      k_agg_f<<<NPAD, 256, 0, stream>>>(fshB, el_cur, er_cur, row_ptr, srcs, bb[l],
                                        WalB[l+1], WredB[l+1], Ahi, Alo, el_nxt, er_nxt);
      float* t1 = el_cur; el_cur = el_nxt; el_nxt = t1;
      float* t2 = er_cur; er_cur = er_nxt; er_nxt = t2;
    } else {
      k_agg_out<<<NNODES, 256, 0, stream>>>(fshB, el_cur, er_cur, row_ptr, srcs, bb[l],
                                            (float*)d_out);
    }
  }
}